// Round 1
// baseline (821.309 us; speedup 1.0000x reference)
//
#include <hip/hip_runtime.h>

typedef __attribute__((ext_vector_type(8))) __bf16 bf16x8;
typedef __attribute__((ext_vector_type(4))) float f32x4;

#define MFMA16(a, b, c) __builtin_amdgcn_mfma_f32_16x16x32_bf16((a), (b), (c), 0, 0, 0)

static constexpr int Bsz = 4, C = 512, N = 2048, H = 8, DH = 64;
static constexpr int BN = Bsz * N;                    // 8192 tokens total
static constexpr size_t BCN = (size_t)Bsz * C * N;    // 4194304 elems per output tensor

// ---------------- workspace layout ----------------
static constexpr size_t SZ_BF = (size_t)BN * C * sizeof(__bf16);  // 8 MiB
static constexpr size_t SZ_W  = (size_t)C * C * sizeof(__bf16);   // 512 KiB
static constexpr size_t SZ_ST = (size_t)Bsz * H * N * sizeof(float);
static constexpr size_t OFF_HT1  = 0;
static constexpr size_t OFF_HT2  = OFF_HT1 + SZ_BF;
static constexpr size_t OFF_Q    = OFF_HT2 + SZ_BF;
static constexpr size_t OFF_K    = OFF_Q + SZ_BF;
static constexpr size_t OFF_VT1  = OFF_K + SZ_BF;    // v1 transposed: [bh][d][N]
static constexpr size_t OFF_VT2  = OFF_VT1 + SZ_BF;
static constexpr size_t OFF_CTX1 = OFF_VT2 + SZ_BF;  // merged ctx1: [(b*N+n)*C + h*64+d]
static constexpr size_t OFF_CTX2 = OFF_CTX1 + SZ_BF;
static constexpr size_t OFF_WQT  = OFF_CTX2 + SZ_BF;
static constexpr size_t OFF_WKT  = OFF_WQT + SZ_W;
static constexpr size_t OFF_WV1T = OFF_WKT + SZ_W;
static constexpr size_t OFF_WV2T = OFF_WV1T + SZ_W;
static constexpr size_t OFF_WO1T = OFF_WV2T + SZ_W;
static constexpr size_t OFF_WO2T = OFF_WO1T + SZ_W;
static constexpr size_t OFF_QMAX = OFF_WO2T + SZ_W;  // per-q stats (max over k)
static constexpr size_t OFF_QSUM = OFF_QMAX + SZ_ST;
static constexpr size_t OFF_KMAX = OFF_QSUM + SZ_ST; // per-k stats (max over q)
static constexpr size_t OFF_KSUM = OFF_KMAX + SZ_ST;

// ---------------- fp32 -> bf16 tiled transpose ----------------
// src: R x S fp32 row-major (+ blockIdx.z * R * S); dst: S x R bf16
__global__ __launch_bounds__(256) void k_tc(const float* __restrict__ src,
                                            __bf16* __restrict__ dst, int R, int S) {
  __shared__ __bf16 tile[64][66];
  size_t boff = (size_t)blockIdx.z * R * S;
  src += boff;
  dst += boff;
  int r0 = blockIdx.y * 64, c0 = blockIdx.x * 64;
  int t = threadIdx.x;
  int cl = t & 63, rr = t >> 6;
  for (int i = 0; i < 16; ++i) {
    int r = rr * 16 + i;
    tile[r][cl] = (__bf16)src[(size_t)(r0 + r) * S + c0 + cl];
  }
  __syncthreads();
  for (int i = 0; i < 16; ++i) {
    int c = rr * 16 + i;
    dst[(size_t)(c0 + c) * R + r0 + cl] = tile[cl][c];
  }
}

// ---------------- GEMM: out = A(8192xC) @ Bt(C cols x C k)^T + bias ----------------
// mode 0: write bf16 q/k layout [bh][n][64]
// mode 1: write bf16 v transposed layout [bh][d][N]
// mode 2: write fp32 [b][col][n] with residual add
__global__ __launch_bounds__(256) void k_gemm(
    const __bf16* __restrict__ A, const __bf16* __restrict__ Bt,
    const float* __restrict__ bias, int mode,
    __bf16* __restrict__ outb, float* __restrict__ outf,
    const float* __restrict__ resid) {
  __shared__ __bf16 As[64][48];
  __shared__ __bf16 Bs[64][48];
  int m0 = blockIdx.x * 64, n0 = blockIdx.y * 64;
  int t = threadIdx.x;
  int lane = t & 63, w = t >> 6;
  int wm = w >> 1, wn = w & 1;
  int l15 = lane & 15, l4 = lane >> 4;
  int srow = t >> 2, skc = (t & 3) * 8;
  f32x4 acc[2][2] = {};
  for (int k0 = 0; k0 < C; k0 += 32) {
    *reinterpret_cast<bf16x8*>(&As[srow][skc]) =
        *reinterpret_cast<const bf16x8*>(&A[(size_t)(m0 + srow) * C + k0 + skc]);
    *reinterpret_cast<bf16x8*>(&Bs[srow][skc]) =
        *reinterpret_cast<const bf16x8*>(&Bt[(size_t)(n0 + srow) * C + k0 + skc]);
    __syncthreads();
    bf16x8 af0 = *reinterpret_cast<const bf16x8*>(&As[wm * 32 + l15][l4 * 8]);
    bf16x8 af1 = *reinterpret_cast<const bf16x8*>(&As[wm * 32 + 16 + l15][l4 * 8]);
    bf16x8 bg0 = *reinterpret_cast<const bf16x8*>(&Bs[wn * 32 + l15][l4 * 8]);
    bf16x8 bg1 = *reinterpret_cast<const bf16x8*>(&Bs[wn * 32 + 16 + l15][l4 * 8]);
    acc[0][0] = MFMA16(af0, bg0, acc[0][0]);
    acc[0][1] = MFMA16(af0, bg1, acc[0][1]);
    acc[1][0] = MFMA16(af1, bg0, acc[1][0]);
    acc[1][1] = MFMA16(af1, bg1, acc[1][1]);
    __syncthreads();
  }
  for (int mi = 0; mi < 2; ++mi)
    for (int ni = 0; ni < 2; ++ni) {
      int gm = m0 + wm * 32 + mi * 16 + l4 * 4;  // token rows gm..gm+3
      int gn = n0 + wn * 32 + ni * 16 + l15;     // output channel
      float bv = bias[gn];
      f32x4 v = acc[mi][ni];
      int b = gm >> 11, n = gm & 2047;
      if (mode == 0) {
        int h = gn >> 6, d = gn & 63;
        size_t base = (size_t)(b * 8 + h) * 2048 + n;
        for (int j = 0; j < 4; ++j) outb[(base + j) * 64 + d] = (__bf16)(v[j] + bv);
      } else if (mode == 1) {
        int h = gn >> 6, d = gn & 63;
        size_t addr = ((size_t)(b * 8 + h) * 64 + d) * 2048 + n;
        union { __bf16 h4[4]; uint2 u; } pk;
        for (int j = 0; j < 4; ++j) pk.h4[j] = (__bf16)(v[j] + bv);
        *reinterpret_cast<uint2*>(&outb[addr]) = pk.u;
      } else {
        size_t addr = ((size_t)b * C + gn) * 2048 + n;
        float4 xv = *reinterpret_cast<const float4*>(&resid[addr]);
        float4 ov;
        ov.x = v[0] + bv + xv.x;
        ov.y = v[1] + bv + xv.y;
        ov.z = v[2] + bv + xv.z;
        ov.w = v[3] + bv + xv.w;
        *reinterpret_cast<float4*>(&outf[addr]) = ov;
      }
    }
}

// ---------------- per-row softmax stats of S = X @ Y^T / 8 ----------------
// X,Y: [bh][2048][64] bf16. Writes max/sumexp over the 2048 cols for each of
// this block's 64 rows.
__global__ __launch_bounds__(256) void k_stats(
    const __bf16* __restrict__ X, const __bf16* __restrict__ Y,
    float* __restrict__ omax, float* __restrict__ osum) {
  int bh = blockIdx.y;
  int r0 = blockIdx.x * 64;
  int t = threadIdx.x, lane = t & 63, w = t >> 6;
  int l15 = lane & 15, l4 = lane >> 4;
  const __bf16* Xb = X + (size_t)bh * N * DH;
  const __bf16* Yb = Y + (size_t)bh * N * DH;
  int rowbase = r0 + w * 16;
  bf16x8 a0 = *reinterpret_cast<const bf16x8*>(&Xb[(size_t)(rowbase + l15) * DH + l4 * 8]);
  bf16x8 a1 = *reinterpret_cast<const bf16x8*>(&Xb[(size_t)(rowbase + l15) * DH + 32 + l4 * 8]);
  float m[4], s[4];
  for (int j = 0; j < 4; ++j) { m[j] = -1e30f; s[j] = 0.f; }
  for (int kc = 0; kc < N; kc += 64) {
    float sc[4][4];
    for (int cg = 0; cg < 4; ++cg) {
      const __bf16* yr = &Yb[(size_t)(kc + cg * 16 + l15) * DH + l4 * 8];
      bf16x8 b0 = *reinterpret_cast<const bf16x8*>(yr);
      bf16x8 b1 = *reinterpret_cast<const bf16x8*>(yr + 32);
      f32x4 acc = {};
      acc = MFMA16(a0, b0, acc);
      acc = MFMA16(a1, b1, acc);
      for (int j = 0; j < 4; ++j) sc[cg][j] = acc[j] * 0.125f;
    }
    for (int j = 0; j < 4; ++j) {
      float cm = fmaxf(fmaxf(sc[0][j], sc[1][j]), fmaxf(sc[2][j], sc[3][j]));
      for (int o = 1; o < 16; o <<= 1) cm = fmaxf(cm, __shfl_xor(cm, o, 64));
      float nm = fmaxf(m[j], cm);
      float ps = expf(sc[0][j] - nm) + expf(sc[1][j] - nm) +
                 expf(sc[2][j] - nm) + expf(sc[3][j] - nm);
      for (int o = 1; o < 16; o <<= 1) ps += __shfl_xor(ps, o, 64);
      s[j] = s[j] * expf(m[j] - nm) + ps;
      m[j] = nm;
    }
  }
  if (l15 == 0) {
    for (int j = 0; j < 4; ++j) {
      int r = rowbase + l4 * 4 + j;
      omax[(size_t)bh * N + r] = m[j];
      osum[(size_t)bh * N + r] = s[j];
    }
  }
}

// ---------------- ctx: out[row,d] = sum_col exp(S-maxc[col])/sumc[col] * V[col,d] --------
// X rows, Y cols, Vt: [bh][d][N] (col-token-major). out: merged [(b*N+row)*C + h*64+d]
__global__ __launch_bounds__(256) void k_ctx(
    const __bf16* __restrict__ X, const __bf16* __restrict__ Y,
    const __bf16* __restrict__ Vt,
    const float* __restrict__ cmax, const float* __restrict__ csum,
    __bf16* __restrict__ out) {
  int bh = blockIdx.y;
  int b = bh >> 3, h = bh & 7;
  int r0 = blockIdx.x * 64;
  int t = threadIdx.x, lane = t & 63, w = t >> 6;
  int l15 = lane & 15, l4 = lane >> 4;
  const __bf16* Xb = X + (size_t)bh * N * DH;
  const __bf16* Yb = Y + (size_t)bh * N * DH;
  const __bf16* Vb = Vt + (size_t)bh * DH * N;
  const float* cm_ = cmax + (size_t)bh * N;
  const float* cs_ = csum + (size_t)bh * N;
  int rowbase = r0 + w * 16;
  bf16x8 a0 = *reinterpret_cast<const bf16x8*>(&Xb[(size_t)(rowbase + l15) * DH + l4 * 8]);
  bf16x8 a1 = *reinterpret_cast<const bf16x8*>(&Xb[(size_t)(rowbase + l15) * DH + 32 + l4 * 8]);
  __shared__ __bf16 P[4][16][72];
  f32x4 oacc[4] = {};
  for (int kc = 0; kc < N; kc += 64) {
    for (int cg = 0; cg < 4; ++cg) {
      const __bf16* yr = &Yb[(size_t)(kc + cg * 16 + l15) * DH + l4 * 8];
      bf16x8 b0 = *reinterpret_cast<const bf16x8*>(yr);
      bf16x8 b1 = *reinterpret_cast<const bf16x8*>(yr + 32);
      f32x4 acc = {};
      acc = MFMA16(a0, b0, acc);
      acc = MFMA16(a1, b1, acc);
      int col = kc + cg * 16 + l15;
      float mm = cm_[col];
      float rs = 1.0f / cs_[col];
      for (int j = 0; j < 4; ++j) {
        float p = expf(acc[j] * 0.125f - mm) * rs;
        P[w][l4 * 4 + j][cg * 16 + l15] = (__bf16)p;
      }
    }
    __syncthreads();
    for (int i = 0; i < 2; ++i) {
      bf16x8 pa = *reinterpret_cast<const bf16x8*>(&P[w][l15][i * 32 + l4 * 8]);
      for (int dg = 0; dg < 4; ++dg) {
        bf16x8 vb = *reinterpret_cast<const bf16x8*>(
            &Vb[(size_t)(dg * 16 + l15) * N + kc + i * 32 + l4 * 8]);
        oacc[dg] = MFMA16(pa, vb, oacc[dg]);
      }
    }
    __syncthreads();
  }
  for (int dg = 0; dg < 4; ++dg) {
    int d = h * 64 + dg * 16 + l15;
    size_t rbase = (size_t)b * N + rowbase + l4 * 4;
    for (int j = 0; j < 4; ++j) out[(rbase + j) * C + d] = (__bf16)oacc[dg][j];
  }
}

extern "C" void kernel_launch(void* const* d_in, const int* in_sizes, int n_in,
                              void* d_out, int out_size, void* d_ws, size_t ws_size,
                              hipStream_t stream) {
  (void)in_sizes; (void)n_in; (void)out_size; (void)ws_size;
  const float* x1  = (const float*)d_in[0];
  const float* x2  = (const float*)d_in[1];
  const float* Wq  = (const float*)d_in[2];
  const float* bq  = (const float*)d_in[3];
  const float* Wk  = (const float*)d_in[4];
  const float* bk  = (const float*)d_in[5];
  const float* Wv1 = (const float*)d_in[6];
  const float* bv1 = (const float*)d_in[7];
  const float* Wv2 = (const float*)d_in[8];
  const float* bv2 = (const float*)d_in[9];
  const float* Wo1 = (const float*)d_in[10];
  const float* bo1 = (const float*)d_in[11];
  const float* Wo2 = (const float*)d_in[12];
  const float* bo2 = (const float*)d_in[13];

  char* ws = (char*)d_ws;
  __bf16* ht1  = (__bf16*)(ws + OFF_HT1);
  __bf16* ht2  = (__bf16*)(ws + OFF_HT2);
  __bf16* qb   = (__bf16*)(ws + OFF_Q);
  __bf16* kb   = (__bf16*)(ws + OFF_K);
  __bf16* vt1  = (__bf16*)(ws + OFF_VT1);
  __bf16* vt2  = (__bf16*)(ws + OFF_VT2);
  __bf16* ctx1 = (__bf16*)(ws + OFF_CTX1);
  __bf16* ctx2 = (__bf16*)(ws + OFF_CTX2);
  __bf16* wqt  = (__bf16*)(ws + OFF_WQT);
  __bf16* wkt  = (__bf16*)(ws + OFF_WKT);
  __bf16* wv1t = (__bf16*)(ws + OFF_WV1T);
  __bf16* wv2t = (__bf16*)(ws + OFF_WV2T);
  __bf16* wo1t = (__bf16*)(ws + OFF_WO1T);
  __bf16* wo2t = (__bf16*)(ws + OFF_WO2T);
  float* qmax = (float*)(ws + OFF_QMAX);
  float* qsum = (float*)(ws + OFF_QSUM);
  float* kmax = (float*)(ws + OFF_KMAX);
  float* ksum = (float*)(ws + OFF_KSUM);
  float* outf = (float*)d_out;

  dim3 blk(256);
  // x -> token-major bf16 (h1, h2)
  k_tc<<<dim3(32, 8, 4), blk, 0, stream>>>(x1, ht1, C, N);
  k_tc<<<dim3(32, 8, 4), blk, 0, stream>>>(x2, ht2, C, N);
  // weights -> transposed bf16 (Wt[j][c])
  k_tc<<<dim3(8, 8, 1), blk, 0, stream>>>(Wq, wqt, C, C);
  k_tc<<<dim3(8, 8, 1), blk, 0, stream>>>(Wk, wkt, C, C);
  k_tc<<<dim3(8, 8, 1), blk, 0, stream>>>(Wv1, wv1t, C, C);
  k_tc<<<dim3(8, 8, 1), blk, 0, stream>>>(Wv2, wv2t, C, C);
  k_tc<<<dim3(8, 8, 1), blk, 0, stream>>>(Wo1, wo1t, C, C);
  k_tc<<<dim3(8, 8, 1), blk, 0, stream>>>(Wo2, wo2t, C, C);

  dim3 gg(BN / 64, C / 64);
  k_gemm<<<gg, blk, 0, stream>>>(ht1, wqt, bq, 0, qb, nullptr, nullptr);
  k_gemm<<<gg, blk, 0, stream>>>(ht2, wkt, bk, 0, kb, nullptr, nullptr);
  k_gemm<<<gg, blk, 0, stream>>>(ht1, wv1t, bv1, 1, vt1, nullptr, nullptr);
  k_gemm<<<gg, blk, 0, stream>>>(ht2, wv2t, bv2, 1, vt2, nullptr, nullptr);

  dim3 gs(N / 64, Bsz * H);
  // per-q stats (softmax over k, for p2/ctx2) and per-k stats (softmax over q, for p1/ctx1)
  k_stats<<<gs, blk, 0, stream>>>(qb, kb, qmax, qsum);
  k_stats<<<gs, blk, 0, stream>>>(kb, qb, kmax, ksum);
  // ctx1[q,d] = sum_k exp(S[q,k]-kmax[k])/ksum[k] * v1[k,d]
  k_ctx<<<gs, blk, 0, stream>>>(qb, kb, vt1, kmax, ksum, ctx1);
  // ctx2[k,d] = sum_q exp(S[q,k]-qmax[q])/qsum[q] * v2[q,d]
  k_ctx<<<gs, blk, 0, stream>>>(kb, qb, vt2, qmax, qsum, ctx2);

  k_gemm<<<gg, blk, 0, stream>>>(ctx1, wo1t, bo1, 2, nullptr, outf, x1);
  k_gemm<<<gg, blk, 0, stream>>>(ctx2, wo2t, bo2, 2, nullptr, outf + BCN, x2);
}

// Round 2
// 365.280 us; speedup vs baseline: 2.2484x; 2.2484x over previous
//
#include <hip/hip_runtime.h>

typedef __attribute__((ext_vector_type(8))) __bf16 bf16x8;
typedef __attribute__((ext_vector_type(4))) float f32x4;
typedef unsigned int u32;

#define MFMA16(a, b, c) __builtin_amdgcn_mfma_f32_16x16x32_bf16((a), (b), (c), 0, 0, 0)
#define EXP2(x) __builtin_amdgcn_exp2f(x)

static constexpr int Bsz = 4, C = 512, N = 2048, H = 8, DH = 64;
static constexpr int BN = Bsz * N;
static constexpr size_t BCN = (size_t)Bsz * C * N;
static constexpr float SM_C = 0.18033688011112042f;  // 0.125 * log2(e)

// async global->LDS, 16B per lane; lds must be wave-uniform base, global is per-lane
__device__ __forceinline__ void gload16(const void* g, void* lds) {
  __builtin_amdgcn_global_load_lds(
      (const __attribute__((address_space(1))) u32*)g,
      (__attribute__((address_space(3))) u32*)lds, 16, 0, 0);
}

// ---------------- workspace layout ----------------
static constexpr size_t SZ_BF = (size_t)BN * C * sizeof(__bf16);
static constexpr size_t SZ_W  = (size_t)C * C * sizeof(__bf16);
static constexpr size_t SZ_ST = (size_t)Bsz * H * N * sizeof(float);
static constexpr size_t OFF_HT1  = 0;
static constexpr size_t OFF_HT2  = OFF_HT1 + SZ_BF;
static constexpr size_t OFF_Q    = OFF_HT2 + SZ_BF;
static constexpr size_t OFF_K    = OFF_Q + SZ_BF;
static constexpr size_t OFF_VT1  = OFF_K + SZ_BF;    // v1 transposed: [bh][d][N]
static constexpr size_t OFF_VT2  = OFF_VT1 + SZ_BF;
static constexpr size_t OFF_CTX1 = OFF_VT2 + SZ_BF;
static constexpr size_t OFF_CTX2 = OFF_CTX1 + SZ_BF;
static constexpr size_t OFF_WQT  = OFF_CTX2 + SZ_BF;
static constexpr size_t OFF_WKT  = OFF_WQT + SZ_W;
static constexpr size_t OFF_WV1T = OFF_WKT + SZ_W;
static constexpr size_t OFF_WV2T = OFF_WV1T + SZ_W;
static constexpr size_t OFF_WO1T = OFF_WV2T + SZ_W;
static constexpr size_t OFF_WO2T = OFF_WO1T + SZ_W;
static constexpr size_t OFF_QMC  = OFF_WO2T + SZ_W;  // per-q: max*SM_C
static constexpr size_t OFF_QRS  = OFF_QMC + SZ_ST;  // per-q: 1/sumexp
static constexpr size_t OFF_KMC  = OFF_QRS + SZ_ST;
static constexpr size_t OFF_KRS  = OFF_KMC + SZ_ST;

// ---------------- fp32 -> bf16 tiled transpose ----------------
__global__ __launch_bounds__(256) void k_tc(const float* __restrict__ src,
                                            __bf16* __restrict__ dst, int R, int S) {
  __shared__ __bf16 tile[64][66];
  size_t boff = (size_t)blockIdx.z * R * S;
  src += boff;
  dst += boff;
  int r0 = blockIdx.y * 64, c0 = blockIdx.x * 64;
  int t = threadIdx.x;
  int cl = t & 63, rr = t >> 6;
#pragma unroll
  for (int i = 0; i < 16; ++i) {
    int r = rr * 16 + i;
    tile[r][cl] = (__bf16)src[(size_t)(r0 + r) * S + c0 + cl];
  }
  __syncthreads();
#pragma unroll
  for (int i = 0; i < 16; ++i) {
    int c = rr * 16 + i;
    dst[(size_t)(c0 + c) * R + r0 + cl] = tile[cl][c];
  }
}

// ---------------- GEMM (m97 structure): 128x128 tile, BK=32 ----------------
// out = A(8192 x 512) @ Bt(512 cols x 512 k)^T + bias
// mode 0: bf16 q/k layout [bh][n][64]; mode 1: bf16 v^T [bh][d][N];
// mode 2: fp32 [b][col][n] + residual
__global__ __launch_bounds__(256) void k_gemm(
    const __bf16* __restrict__ A, const __bf16* __restrict__ Bt,
    const float* __restrict__ bias, int mode,
    __bf16* __restrict__ outb, float* __restrict__ outf,
    const float* __restrict__ resid) {
  __shared__ __bf16 As[128 * 32];
  __shared__ __bf16 Bs[128 * 32];
  int m0 = blockIdx.x * 128, n0 = blockIdx.y * 128;
  int t = threadIdx.x, lane = t & 63, w = t >> 6;
  int wm = w >> 1, wn = w & 1;
  int l15 = lane & 15, l4 = lane >> 4;
  int srow = t >> 2;           // 0..63
  int scol = (t & 3) * 8;      // elems
  char* abase0 = (char*)As + w * 1024;
  char* abase1 = (char*)As + 4096 + w * 1024;
  char* bbase0 = (char*)Bs + w * 1024;
  char* bbase1 = (char*)Bs + 4096 + w * 1024;
  f32x4 acc[4][4] = {};
  for (int k0 = 0; k0 < C; k0 += 32) {
    gload16(&A[(size_t)(m0 + srow) * C + k0 + scol], abase0);
    gload16(&A[(size_t)(m0 + 64 + srow) * C + k0 + scol], abase1);
    gload16(&Bt[(size_t)(n0 + srow) * C + k0 + scol], bbase0);
    gload16(&Bt[(size_t)(n0 + 64 + srow) * C + k0 + scol], bbase1);
    __syncthreads();
    bf16x8 af[4], bfr[4];
#pragma unroll
    for (int i = 0; i < 4; ++i)
      af[i] = *(const bf16x8*)&As[(wm * 64 + i * 16 + l15) * 32 + l4 * 8];
#pragma unroll
    for (int i = 0; i < 4; ++i)
      bfr[i] = *(const bf16x8*)&Bs[(wn * 64 + i * 16 + l15) * 32 + l4 * 8];
#pragma unroll
    for (int mi = 0; mi < 4; ++mi)
#pragma unroll
      for (int ni = 0; ni < 4; ++ni)
        acc[mi][ni] = MFMA16(af[mi], bfr[ni], acc[mi][ni]);
    __syncthreads();
  }
#pragma unroll
  for (int mi = 0; mi < 4; ++mi)
#pragma unroll
    for (int ni = 0; ni < 4; ++ni) {
      int gm = m0 + wm * 64 + mi * 16 + l4 * 4;  // token rows gm..gm+3
      int gn = n0 + wn * 64 + ni * 16 + l15;     // output channel
      float bv = bias[gn];
      f32x4 v = acc[mi][ni];
      int b = gm >> 11, n = gm & 2047;
      if (mode == 0) {
        int h = gn >> 6, d = gn & 63;
        size_t base = (size_t)(b * 8 + h) * 2048 + n;
#pragma unroll
        for (int j = 0; j < 4; ++j) outb[(base + j) * 64 + d] = (__bf16)(v[j] + bv);
      } else if (mode == 1) {
        int h = gn >> 6, d = gn & 63;
        size_t addr = ((size_t)(b * 8 + h) * 64 + d) * 2048 + n;
        union { __bf16 h4[4]; uint2 u; } pk;
#pragma unroll
        for (int j = 0; j < 4; ++j) pk.h4[j] = (__bf16)(v[j] + bv);
        *reinterpret_cast<uint2*>(&outb[addr]) = pk.u;
      } else {
        size_t addr = ((size_t)b * C + gn) * 2048 + n;
        float4 xv = *reinterpret_cast<const float4*>(&resid[addr]);
        float4 ov;
        ov.x = v[0] + bv + xv.x;
        ov.y = v[1] + bv + xv.y;
        ov.z = v[2] + bv + xv.z;
        ov.w = v[3] + bv + xv.w;
        *reinterpret_cast<float4*>(&outf[addr]) = ov;
      }
    }
}

// ---------------- per-row softmax stats of S = X @ Y^T (scaled by 0.125) -------
// Writes m*SM_C and 1/sumexp for each row (reduction over all 2048 cols).
__global__ __launch_bounds__(512, 4) void k_stats(
    const __bf16* __restrict__ X, const __bf16* __restrict__ Y,
    float* __restrict__ omc, float* __restrict__ ors) {
  __shared__ __bf16 Ys[64 * 64];
  int bh = blockIdx.y;
  int t = threadIdx.x, lane = t & 63, w = t >> 6;
  int l15 = lane & 15, l4 = lane >> 4;
  const __bf16* Xb = X + (size_t)bh * N * DH;
  const __bf16* Yb = Y + (size_t)bh * N * DH;
  int rowbase = blockIdx.x * 128 + w * 16;
  bf16x8 a0 = *(const bf16x8*)&Xb[(size_t)(rowbase + l15) * DH + l4 * 8];
  bf16x8 a1 = *(const bf16x8*)&Xb[(size_t)(rowbase + l15) * DH + 32 + l4 * 8];
  int srow = t >> 3;
  int sc8 = ((t & 7) ^ (srow & 7)) * 8;   // swizzled source col (elems)
  char* ydst = (char*)Ys + w * 1024;
  const char* ysb = (const char*)Ys;
  float m[4], s[4];
#pragma unroll
  for (int j = 0; j < 4; ++j) { m[j] = -1e30f; s[j] = 0.f; }
  for (int kc = 0; kc < N; kc += 64) {
    gload16(&Yb[(size_t)(kc + srow) * DH + sc8], ydst);
    __syncthreads();
    f32x4 sc[4];
#pragma unroll
    for (int cg = 0; cg < 4; ++cg) {
      int row = cg * 16 + l15;
      int sw = (row & 7) << 4;
      bf16x8 b0 = *(const bf16x8*)(ysb + row * 128 + ((l4 * 16) ^ sw));
      bf16x8 b1 = *(const bf16x8*)(ysb + row * 128 + ((64 + l4 * 16) ^ sw));
      f32x4 acc = {};
      acc = MFMA16(a0, b0, acc);
      acc = MFMA16(a1, b1, acc);
      sc[cg] = acc;
    }
#pragma unroll
    for (int j = 0; j < 4; ++j) {
      float v0 = sc[0][j], v1 = sc[1][j], v2 = sc[2][j], v3 = sc[3][j];
      float vm = fmaxf(fmaxf(v0, v1), fmaxf(v2, v3));
      float nm = fmaxf(m[j], vm);
      float nmc = nm * SM_C;
      float resc = EXP2(__builtin_fmaf(m[j], SM_C, -nmc));
      float ps = EXP2(__builtin_fmaf(v0, SM_C, -nmc)) + EXP2(__builtin_fmaf(v1, SM_C, -nmc)) +
                 EXP2(__builtin_fmaf(v2, SM_C, -nmc)) + EXP2(__builtin_fmaf(v3, SM_C, -nmc));
      s[j] = __builtin_fmaf(s[j], resc, ps);
      m[j] = nm;
    }
    __syncthreads();
  }
#pragma unroll
  for (int j = 0; j < 4; ++j) {
    for (int o = 1; o < 16; o <<= 1) {
      float om = __shfl_xor(m[j], o, 64);
      float os = __shfl_xor(s[j], o, 64);
      float nm = fmaxf(m[j], om);
      s[j] = s[j] * EXP2((m[j] - nm) * SM_C) + os * EXP2((om - nm) * SM_C);
      m[j] = nm;
    }
  }
  if (l15 == 0) {
#pragma unroll
    for (int j = 0; j < 4; ++j) {
      int r = rowbase + l4 * 4 + j;
      omc[(size_t)bh * N + r] = m[j] * SM_C;
      ors[(size_t)bh * N + r] = 1.0f / s[j];
    }
  }
}

// ---------------- ctx: out[row,d] = sum_col exp2(S*c - mc[col])*rs[col] * V[col,d] ----
__global__ __launch_bounds__(512, 4) void k_ctx(
    const __bf16* __restrict__ X, const __bf16* __restrict__ Y,
    const __bf16* __restrict__ Vt,
    const float* __restrict__ cmc, const float* __restrict__ crs,
    __bf16* __restrict__ out) {
  __shared__ __bf16 Ys[64 * 64];
  __shared__ __bf16 Vs[64 * 64];
  __shared__ __bf16 Ps[8][16][80];
  int bh = blockIdx.y;
  int b = bh >> 3, h = bh & 7;
  int t = threadIdx.x, lane = t & 63, w = t >> 6;
  int l15 = lane & 15, l4 = lane >> 4;
  const __bf16* Xb = X + (size_t)bh * N * DH;
  const __bf16* Yb = Y + (size_t)bh * N * DH;
  const __bf16* Vb = Vt + (size_t)bh * DH * N;
  const float* mc_ = cmc + (size_t)bh * N;
  const float* rs_ = crs + (size_t)bh * N;
  int rowbase = blockIdx.x * 128 + w * 16;
  bf16x8 a0 = *(const bf16x8*)&Xb[(size_t)(rowbase + l15) * DH + l4 * 8];
  bf16x8 a1 = *(const bf16x8*)&Xb[(size_t)(rowbase + l15) * DH + 32 + l4 * 8];
  int srow = t >> 3;
  int sc8 = ((t & 7) ^ (srow & 7)) * 8;
  char* ydst = (char*)Ys + w * 1024;
  char* vdst = (char*)Vs + w * 1024;
  const char* ysb = (const char*)Ys;
  const char* vsb = (const char*)Vs;
  f32x4 oacc[4] = {};
  for (int kc = 0; kc < N; kc += 64) {
    gload16(&Yb[(size_t)(kc + srow) * DH + sc8], ydst);
    gload16(&Vb[(size_t)srow * N + kc + sc8], vdst);
    __syncthreads();
    // phase 1: S tile + softmax weights -> per-wave Ps
#pragma unroll
    for (int cg = 0; cg < 4; ++cg) {
      int row = cg * 16 + l15;
      int sw = (row & 7) << 4;
      bf16x8 b0 = *(const bf16x8*)(ysb + row * 128 + ((l4 * 16) ^ sw));
      bf16x8 b1 = *(const bf16x8*)(ysb + row * 128 + ((64 + l4 * 16) ^ sw));
      f32x4 acc = {};
      acc = MFMA16(a0, b0, acc);
      acc = MFMA16(a1, b1, acc);
      int col = kc + row;
      float mc = mc_[col], rs = rs_[col];
#pragma unroll
      for (int j = 0; j < 4; ++j) {
        float p = EXP2(__builtin_fmaf(acc[j], SM_C, -mc)) * rs;
        Ps[w][l4 * 4 + j][cg * 16 + l15] = (__bf16)p;
      }
    }
    // phase 2: PV (same-wave LDS ordering; no barrier needed for Ps)
#pragma unroll
    for (int i = 0; i < 2; ++i) {
      bf16x8 pa = *(const bf16x8*)&Ps[w][l15][i * 32 + l4 * 8];
#pragma unroll
      for (int dg = 0; dg < 4; ++dg) {
        int vrow = dg * 16 + l15;
        int vsw = (vrow & 7) << 4;
        bf16x8 vb = *(const bf16x8*)(vsb + vrow * 128 + ((i * 64 + l4 * 16) ^ vsw));
        oacc[dg] = MFMA16(pa, vb, oacc[dg]);
      }
    }
    __syncthreads();
  }
#pragma unroll
  for (int dg = 0; dg < 4; ++dg) {
    int d = h * 64 + dg * 16 + l15;
    size_t rbase = (size_t)b * N + rowbase + l4 * 4;
#pragma unroll
    for (int j = 0; j < 4; ++j) out[(rbase + j) * C + d] = (__bf16)oacc[dg][j];
  }
}

extern "C" void kernel_launch(void* const* d_in, const int* in_sizes, int n_in,
                              void* d_out, int out_size, void* d_ws, size_t ws_size,
                              hipStream_t stream) {
  (void)in_sizes; (void)n_in; (void)out_size; (void)ws_size;
  const float* x1  = (const float*)d_in[0];
  const float* x2  = (const float*)d_in[1];
  const float* Wq  = (const float*)d_in[2];
  const float* bq  = (const float*)d_in[3];
  const float* Wk  = (const float*)d_in[4];
  const float* bk  = (const float*)d_in[5];
  const float* Wv1 = (const float*)d_in[6];
  const float* bv1 = (const float*)d_in[7];
  const float* Wv2 = (const float*)d_in[8];
  const float* bv2 = (const float*)d_in[9];
  const float* Wo1 = (const float*)d_in[10];
  const float* bo1 = (const float*)d_in[11];
  const float* Wo2 = (const float*)d_in[12];
  const float* bo2 = (const float*)d_in[13];

  char* ws = (char*)d_ws;
  __bf16* ht1  = (__bf16*)(ws + OFF_HT1);
  __bf16* ht2  = (__bf16*)(ws + OFF_HT2);
  __bf16* qb   = (__bf16*)(ws + OFF_Q);
  __bf16* kb   = (__bf16*)(ws + OFF_K);
  __bf16* vt1  = (__bf16*)(ws + OFF_VT1);
  __bf16* vt2  = (__bf16*)(ws + OFF_VT2);
  __bf16* ctx1 = (__bf16*)(ws + OFF_CTX1);
  __bf16* ctx2 = (__bf16*)(ws + OFF_CTX2);
  __bf16* wqt  = (__bf16*)(ws + OFF_WQT);
  __bf16* wkt  = (__bf16*)(ws + OFF_WKT);
  __bf16* wv1t = (__bf16*)(ws + OFF_WV1T);
  __bf16* wv2t = (__bf16*)(ws + OFF_WV2T);
  __bf16* wo1t = (__bf16*)(ws + OFF_WO1T);
  __bf16* wo2t = (__bf16*)(ws + OFF_WO2T);
  float* qmc = (float*)(ws + OFF_QMC);
  float* qrs = (float*)(ws + OFF_QRS);
  float* kmc = (float*)(ws + OFF_KMC);
  float* krs = (float*)(ws + OFF_KRS);
  float* outf = (float*)d_out;

  dim3 blk(256);
  k_tc<<<dim3(32, 8, 4), blk, 0, stream>>>(x1, ht1, C, N);
  k_tc<<<dim3(32, 8, 4), blk, 0, stream>>>(x2, ht2, C, N);
  k_tc<<<dim3(8, 8, 1), blk, 0, stream>>>(Wq, wqt, C, C);
  k_tc<<<dim3(8, 8, 1), blk, 0, stream>>>(Wk, wkt, C, C);
  k_tc<<<dim3(8, 8, 1), blk, 0, stream>>>(Wv1, wv1t, C, C);
  k_tc<<<dim3(8, 8, 1), blk, 0, stream>>>(Wv2, wv2t, C, C);
  k_tc<<<dim3(8, 8, 1), blk, 0, stream>>>(Wo1, wo1t, C, C);
  k_tc<<<dim3(8, 8, 1), blk, 0, stream>>>(Wo2, wo2t, C, C);

  dim3 gg(BN / 128, C / 128);
  k_gemm<<<gg, blk, 0, stream>>>(ht1, wqt, bq, 0, qb, nullptr, nullptr);
  k_gemm<<<gg, blk, 0, stream>>>(ht2, wkt, bk, 0, kb, nullptr, nullptr);
  k_gemm<<<gg, blk, 0, stream>>>(ht1, wv1t, bv1, 1, vt1, nullptr, nullptr);
  k_gemm<<<gg, blk, 0, stream>>>(ht2, wv2t, bv2, 1, vt2, nullptr, nullptr);

  dim3 gs(N / 128, Bsz * H);
  dim3 blk512(512);
  k_stats<<<gs, blk512, 0, stream>>>(qb, kb, qmc, qrs);
  k_stats<<<gs, blk512, 0, stream>>>(kb, qb, kmc, krs);
  k_ctx<<<gs, blk512, 0, stream>>>(qb, kb, vt1, kmc, krs, ctx1);
  k_ctx<<<gs, blk512, 0, stream>>>(kb, qb, vt2, qmc, qrs, ctx2);

  k_gemm<<<gg, blk, 0, stream>>>(ctx1, wo1t, bo1, 2, nullptr, outf, x1);
  k_gemm<<<gg, blk, 0, stream>>>(ctx2, wo2t, bo2, 2, nullptr, outf + BCN, x2);
}

// Round 3
// 262.072 us; speedup vs baseline: 3.1339x; 1.3938x over previous
//
#include <hip/hip_runtime.h>

typedef __attribute__((ext_vector_type(8))) __bf16 bf16x8;
typedef __attribute__((ext_vector_type(4))) __bf16 bf16x4;
typedef __attribute__((ext_vector_type(4))) float f32x4;
typedef unsigned int u32;

#define MFMA16(a, b, c) __builtin_amdgcn_mfma_f32_16x16x32_bf16((a), (b), (c), 0, 0, 0)
#define EXP2(x) __builtin_amdgcn_exp2f(x)

static constexpr int Bsz = 4, C = 512, N = 2048, H = 8, DH = 64;
static constexpr int BN = Bsz * N;
static constexpr size_t BCN = (size_t)Bsz * C * N;
static constexpr float SM_C = 0.18033688011112042f;  // 0.125 * log2(e)

// async global->LDS, 16B per lane; lds dest: wave-uniform base + lane*16
__device__ __forceinline__ void gload16(const void* g, void* lds) {
  __builtin_amdgcn_global_load_lds(
      (const __attribute__((address_space(1))) u32*)g,
      (__attribute__((address_space(3))) u32*)lds, 16, 0, 0);
}

// ---------------- workspace layout ----------------
static constexpr size_t SZ_BF = (size_t)BN * C * sizeof(__bf16);
static constexpr size_t SZ_W  = (size_t)C * C * sizeof(__bf16);
static constexpr size_t SZ_ST = (size_t)Bsz * H * N * sizeof(float);
static constexpr size_t OFF_HT1  = 0;
static constexpr size_t OFF_HT2  = OFF_HT1 + SZ_BF;
static constexpr size_t OFF_Q    = OFF_HT2 + SZ_BF;
static constexpr size_t OFF_K    = OFF_Q + SZ_BF;
static constexpr size_t OFF_VT1  = OFF_K + SZ_BF;    // v1^T (pre-scaled): [bh][d][N]
static constexpr size_t OFF_VT2  = OFF_VT1 + SZ_BF;
static constexpr size_t OFF_CTX1 = OFF_VT2 + SZ_BF;
static constexpr size_t OFF_CTX2 = OFF_CTX1 + SZ_BF;
static constexpr size_t OFF_WQT  = OFF_CTX2 + SZ_BF;
static constexpr size_t OFF_WKT  = OFF_WQT + SZ_W;
static constexpr size_t OFF_WV1T = OFF_WKT + SZ_W;
static constexpr size_t OFF_WV2T = OFF_WV1T + SZ_W;
static constexpr size_t OFF_WO1T = OFF_WV2T + SZ_W;
static constexpr size_t OFF_WO2T = OFF_WO1T + SZ_W;
static constexpr size_t OFF_QRS  = OFF_WO2T + SZ_W;  // per-q: 1/sum_k exp2(S*c)
static constexpr size_t OFF_KRS  = OFF_QRS + SZ_ST;  // per-k: 1/sum_q exp2(S*c)

// ---------------- fp32 -> bf16 tiled transpose (x inputs) ----------------
__global__ __launch_bounds__(256) void k_tc(const float* __restrict__ src,
                                            __bf16* __restrict__ dst, int R, int S) {
  __shared__ __bf16 tile[64][66];
  size_t boff = (size_t)blockIdx.z * R * S;
  src += boff;
  dst += boff;
  int r0 = blockIdx.y * 64, c0 = blockIdx.x * 64;
  int t = threadIdx.x;
  int cl = t & 63, rr = t >> 6;
#pragma unroll
  for (int i = 0; i < 16; ++i) {
    int r = rr * 16 + i;
    tile[r][cl] = (__bf16)src[(size_t)(r0 + r) * S + c0 + cl];
  }
  __syncthreads();
#pragma unroll
  for (int i = 0; i < 16; ++i) {
    int c = rr * 16 + i;
    dst[(size_t)(c0 + c) * R + r0 + cl] = tile[cl][c];
  }
}

// all six 512x512 weight transposes in one dispatch (z = which weight)
struct WT6 {
  const float* src[6];
  __bf16* dst[6];
};
__global__ __launch_bounds__(256) void k_tcw(WT6 p) {
  __shared__ __bf16 tile[64][66];
  int z = blockIdx.z;
  const float* src = p.src[z];
  __bf16* dst = p.dst[z];
  int r0 = blockIdx.y * 64, c0 = blockIdx.x * 64;
  int t = threadIdx.x;
  int cl = t & 63, rr = t >> 6;
#pragma unroll
  for (int i = 0; i < 16; ++i) {
    int r = rr * 16 + i;
    tile[r][cl] = (__bf16)src[(size_t)(r0 + r) * C + c0 + cl];
  }
  __syncthreads();
#pragma unroll
  for (int i = 0; i < 16; ++i) {
    int c = rr * 16 + i;
    dst[(size_t)(c0 + c) * C + r0 + cl] = tile[cl][c];
  }
}

// ---------------- GEMM (m97 structure): 128x128 tile, BK=32 ----------------
// mode 0: bf16 q/k layout [bh][n][64], out = (acc+bias)*scale
// mode 1: bf16 v^T layout [bh][d][N], out = (acc+bias)*rs[bh][token]
// mode 2: fp32 [b][col][n] + residual
__global__ __launch_bounds__(256) void k_gemm(
    const __bf16* __restrict__ A, const __bf16* __restrict__ Bt,
    const float* __restrict__ bias, int mode, float scale,
    const float* __restrict__ rs,
    __bf16* __restrict__ outb, float* __restrict__ outf,
    const float* __restrict__ resid) {
  __shared__ __bf16 As[128 * 32];
  __shared__ __bf16 Bs[128 * 32];
  int m0 = blockIdx.x * 128, n0 = blockIdx.y * 128;
  int t = threadIdx.x, lane = t & 63, w = t >> 6;
  int wm = w >> 1, wn = w & 1;
  int l15 = lane & 15, l4 = lane >> 4;
  int srow = t >> 2;
  int scol = (t & 3) * 8;
  char* abase0 = (char*)As + w * 1024;
  char* abase1 = (char*)As + 4096 + w * 1024;
  char* bbase0 = (char*)Bs + w * 1024;
  char* bbase1 = (char*)Bs + 4096 + w * 1024;
  f32x4 acc[4][4] = {};
  for (int k0 = 0; k0 < C; k0 += 32) {
    gload16(&A[(size_t)(m0 + srow) * C + k0 + scol], abase0);
    gload16(&A[(size_t)(m0 + 64 + srow) * C + k0 + scol], abase1);
    gload16(&Bt[(size_t)(n0 + srow) * C + k0 + scol], bbase0);
    gload16(&Bt[(size_t)(n0 + 64 + srow) * C + k0 + scol], bbase1);
    __syncthreads();
    bf16x8 af[4], bfr[4];
#pragma unroll
    for (int i = 0; i < 4; ++i)
      af[i] = *(const bf16x8*)&As[(wm * 64 + i * 16 + l15) * 32 + l4 * 8];
#pragma unroll
    for (int i = 0; i < 4; ++i)
      bfr[i] = *(const bf16x8*)&Bs[(wn * 64 + i * 16 + l15) * 32 + l4 * 8];
#pragma unroll
    for (int mi = 0; mi < 4; ++mi)
#pragma unroll
      for (int ni = 0; ni < 4; ++ni)
        acc[mi][ni] = MFMA16(af[mi], bfr[ni], acc[mi][ni]);
    __syncthreads();
  }
#pragma unroll
  for (int mi = 0; mi < 4; ++mi)
#pragma unroll
    for (int ni = 0; ni < 4; ++ni) {
      int gm = m0 + wm * 64 + mi * 16 + l4 * 4;  // token rows gm..gm+3
      int gn = n0 + wn * 64 + ni * 16 + l15;     // output channel
      float bv = bias[gn];
      f32x4 v = acc[mi][ni];
      int b = gm >> 11, n = gm & 2047;
      if (mode == 0) {
        int h = gn >> 6, d = gn & 63;
        size_t base = (size_t)(b * 8 + h) * 2048 + n;
#pragma unroll
        for (int j = 0; j < 4; ++j)
          outb[(base + j) * 64 + d] = (__bf16)((v[j] + bv) * scale);
      } else if (mode == 1) {
        int h = gn >> 6, d = gn & 63;
        size_t tok = (size_t)(b * 8 + h) * 2048 + n;
        float4 rv = *reinterpret_cast<const float4*>(&rs[tok]);
        size_t addr = ((size_t)(b * 8 + h) * 64 + d) * 2048 + n;
        union { __bf16 h4[4]; uint2 u; } pk;
        pk.h4[0] = (__bf16)((v[0] + bv) * rv.x);
        pk.h4[1] = (__bf16)((v[1] + bv) * rv.y);
        pk.h4[2] = (__bf16)((v[2] + bv) * rv.z);
        pk.h4[3] = (__bf16)((v[3] + bv) * rv.w);
        *reinterpret_cast<uint2*>(&outb[addr]) = pk.u;
      } else {
        size_t addr = ((size_t)b * C + gn) * 2048 + n;
        float4 xv = *reinterpret_cast<const float4*>(&resid[addr]);
        float4 ov;
        ov.x = v[0] + bv + xv.x;
        ov.y = v[1] + bv + xv.y;
        ov.z = v[2] + bv + xv.z;
        ov.w = v[3] + bv + xv.w;
        *reinterpret_cast<float4*>(&outf[addr]) = ov;
      }
    }
}

// ---------------- row sums of exp2(S) where S = X @ Y^T (q pre-scaled) -------
// writes 1/sum for each X-row. 4 waves x 32 q-rows = 128 q / block.
__global__ __launch_bounds__(256, 4) void k_stats(
    const __bf16* __restrict__ X, const __bf16* __restrict__ Y,
    float* __restrict__ ors) {
  __shared__ __bf16 Ys[64 * 64];
  int bh = blockIdx.y;
  int t = threadIdx.x, lane = t & 63, w = t >> 6;
  int l15 = lane & 15, l4 = lane >> 4;
  const __bf16* Xb = X + (size_t)bh * N * DH;
  const __bf16* Yb = Y + (size_t)bh * N * DH;
  int rowbase = blockIdx.x * 128 + w * 32;
  bf16x8 a[2][2];
#pragma unroll
  for (int rg = 0; rg < 2; ++rg)
#pragma unroll
    for (int hf = 0; hf < 2; ++hf)
      a[rg][hf] = *(const bf16x8*)&Xb[(size_t)(rowbase + rg * 16 + l15) * DH + hf * 32 + l4 * 8];
  int srow = t >> 3;
  int sc8 = ((t & 7) ^ (srow & 7)) * 8;  // pre-swizzled source col (elems)
  char* yd0 = (char*)Ys + w * 1024;
  char* yd1 = (char*)Ys + 4096 + w * 1024;
  const char* ysb = (const char*)Ys;
  float s[2][4] = {};
  for (int kc = 0; kc < N; kc += 64) {
    gload16(&Yb[(size_t)(kc + srow) * DH + sc8], yd0);
    gload16(&Yb[(size_t)(kc + 32 + srow) * DH + sc8], yd1);
    __syncthreads();
    bf16x8 bfr[4][2];
#pragma unroll
    for (int cg = 0; cg < 4; ++cg) {
      int row = cg * 16 + l15;
      int sw = (row & 7) << 4;
      bfr[cg][0] = *(const bf16x8*)(ysb + row * 128 + ((l4 * 16) ^ sw));
      bfr[cg][1] = *(const bf16x8*)(ysb + row * 128 + ((64 + l4 * 16) ^ sw));
    }
#pragma unroll
    for (int rg = 0; rg < 2; ++rg) {
      f32x4 acc[4] = {};
#pragma unroll
      for (int cg = 0; cg < 4; ++cg) {
        acc[cg] = MFMA16(a[rg][0], bfr[cg][0], acc[cg]);
        acc[cg] = MFMA16(a[rg][1], bfr[cg][1], acc[cg]);
      }
#pragma unroll
      for (int cg = 0; cg < 4; ++cg)
#pragma unroll
        for (int j = 0; j < 4; ++j) s[rg][j] += EXP2(acc[cg][j]);
    }
    __syncthreads();
  }
#pragma unroll
  for (int rg = 0; rg < 2; ++rg)
#pragma unroll
    for (int j = 0; j < 4; ++j) {
      float v = s[rg][j];
      v += __shfl_xor(v, 1, 64);
      v += __shfl_xor(v, 2, 64);
      v += __shfl_xor(v, 4, 64);
      v += __shfl_xor(v, 8, 64);
      if (l15 == 0)
        ors[(size_t)bh * N + rowbase + rg * 16 + l4 * 4 + j] = 1.0f / v;
    }
}

// ---------------- ctx: out[q,d] = sum_c exp2(S[q,c]) * V'[c,d] ----------------
// S^T via mfma(Y, X): lane holds 4 consecutive cols for fixed q -> packed P store.
// PV via mfma(V, P): lane holds 4 consecutive d for fixed q -> packed out store.
__global__ __launch_bounds__(256, 2) void k_ctx(
    const __bf16* __restrict__ X, const __bf16* __restrict__ Y,
    const __bf16* __restrict__ Vt, __bf16* __restrict__ out) {
  __shared__ __bf16 Ys[64 * 64];
  __shared__ __bf16 Vs[64 * 64];
  __shared__ __bf16 Ps[4][16][72];  // per-wave P: [q 16][c 64+pad], 144B row stride
  int bh = blockIdx.y;
  int b = bh >> 3, h = bh & 7;
  int t = threadIdx.x, lane = t & 63, w = t >> 6;
  int l15 = lane & 15, l4 = lane >> 4;
  const __bf16* Xb = X + (size_t)bh * N * DH;
  const __bf16* Yb = Y + (size_t)bh * N * DH;
  const __bf16* Vb = Vt + (size_t)bh * DH * N;
  int rowbase = blockIdx.x * 128 + w * 32;
  bf16x8 a[2][2];
#pragma unroll
  for (int rg = 0; rg < 2; ++rg)
#pragma unroll
    for (int hf = 0; hf < 2; ++hf)
      a[rg][hf] = *(const bf16x8*)&Xb[(size_t)(rowbase + rg * 16 + l15) * DH + hf * 32 + l4 * 8];
  int srow = t >> 3;
  int sc8 = ((t & 7) ^ (srow & 7)) * 8;
  char* yd0 = (char*)Ys + w * 1024;
  char* yd1 = (char*)Ys + 4096 + w * 1024;
  char* vd0 = (char*)Vs + w * 1024;
  char* vd1 = (char*)Vs + 4096 + w * 1024;
  const char* ysb = (const char*)Ys;
  const char* vsb = (const char*)Vs;
  f32x4 oacc[2][4] = {};
  for (int kc = 0; kc < N; kc += 64) {
    gload16(&Yb[(size_t)(kc + srow) * DH + sc8], yd0);
    gload16(&Yb[(size_t)(kc + 32 + srow) * DH + sc8], yd1);
    gload16(&Vb[(size_t)srow * N + kc + sc8], vd0);
    gload16(&Vb[(size_t)(32 + srow) * N + kc + sc8], vd1);
    __syncthreads();
    bf16x8 yf[4][2], vf[4][2];
#pragma unroll
    for (int cg = 0; cg < 4; ++cg) {
      int row = cg * 16 + l15;
      int sw = (row & 7) << 4;
      yf[cg][0] = *(const bf16x8*)(ysb + row * 128 + ((l4 * 16) ^ sw));
      yf[cg][1] = *(const bf16x8*)(ysb + row * 128 + ((64 + l4 * 16) ^ sw));
      vf[cg][0] = *(const bf16x8*)(vsb + row * 128 + ((l4 * 16) ^ sw));
      vf[cg][1] = *(const bf16x8*)(vsb + row * 128 + ((64 + l4 * 16) ^ sw));
    }
#pragma unroll
    for (int rg = 0; rg < 2; ++rg) {
      // S^T tile: D[c = cg*16 + l4*4 + j][q = l15]
      f32x4 acc[4] = {};
#pragma unroll
      for (int cg = 0; cg < 4; ++cg) {
        acc[cg] = MFMA16(yf[cg][0], a[rg][0], acc[cg]);
        acc[cg] = MFMA16(yf[cg][1], a[rg][1], acc[cg]);
      }
      // P = exp2(S), packed store: row q=l15, cols cg*16+l4*4 .. +3
#pragma unroll
      for (int cg = 0; cg < 4; ++cg) {
        bf16x4 pk;
#pragma unroll
        for (int j = 0; j < 4; ++j) pk[j] = (__bf16)EXP2(acc[cg][j]);
        *(bf16x4*)&Ps[w][l15][cg * 16 + l4 * 4] = pk;
      }
      // PV: oacc[rg][dg] over c in this 64-chunk
#pragma unroll
      for (int i = 0; i < 2; ++i) {
        bf16x8 pf = *(const bf16x8*)&Ps[w][l15][i * 32 + l4 * 8];
#pragma unroll
        for (int dg = 0; dg < 4; ++dg)
          oacc[rg][dg] = MFMA16(vf[dg][i], pf, oacc[rg][dg]);
      }
    }
    __syncthreads();
  }
#pragma unroll
  for (int rg = 0; rg < 2; ++rg)
#pragma unroll
    for (int dg = 0; dg < 4; ++dg) {
      bf16x4 pk;
#pragma unroll
      for (int j = 0; j < 4; ++j) pk[j] = (__bf16)oacc[rg][dg][j];
      size_t addr = ((size_t)b * N + rowbase + rg * 16 + l15) * C + h * 64 + dg * 16 + l4 * 4;
      *(bf16x4*)&out[addr] = pk;
    }
}

extern "C" void kernel_launch(void* const* d_in, const int* in_sizes, int n_in,
                              void* d_out, int out_size, void* d_ws, size_t ws_size,
                              hipStream_t stream) {
  (void)in_sizes; (void)n_in; (void)out_size; (void)ws_size;
  const float* x1  = (const float*)d_in[0];
  const float* x2  = (const float*)d_in[1];
  const float* Wq  = (const float*)d_in[2];
  const float* bq  = (const float*)d_in[3];
  const float* Wk  = (const float*)d_in[4];
  const float* bk  = (const float*)d_in[5];
  const float* Wv1 = (const float*)d_in[6];
  const float* bv1 = (const float*)d_in[7];
  const float* Wv2 = (const float*)d_in[8];
  const float* bv2 = (const float*)d_in[9];
  const float* Wo1 = (const float*)d_in[10];
  const float* bo1 = (const float*)d_in[11];
  const float* Wo2 = (const float*)d_in[12];
  const float* bo2 = (const float*)d_in[13];

  char* ws = (char*)d_ws;
  __bf16* ht1  = (__bf16*)(ws + OFF_HT1);
  __bf16* ht2  = (__bf16*)(ws + OFF_HT2);
  __bf16* qb   = (__bf16*)(ws + OFF_Q);
  __bf16* kb   = (__bf16*)(ws + OFF_K);
  __bf16* vt1  = (__bf16*)(ws + OFF_VT1);
  __bf16* vt2  = (__bf16*)(ws + OFF_VT2);
  __bf16* ctx1 = (__bf16*)(ws + OFF_CTX1);
  __bf16* ctx2 = (__bf16*)(ws + OFF_CTX2);
  __bf16* wqt  = (__bf16*)(ws + OFF_WQT);
  __bf16* wkt  = (__bf16*)(ws + OFF_WKT);
  __bf16* wv1t = (__bf16*)(ws + OFF_WV1T);
  __bf16* wv2t = (__bf16*)(ws + OFF_WV2T);
  __bf16* wo1t = (__bf16*)(ws + OFF_WO1T);
  __bf16* wo2t = (__bf16*)(ws + OFF_WO2T);
  float* qrs = (float*)(ws + OFF_QRS);
  float* krs = (float*)(ws + OFF_KRS);
  float* outf = (float*)d_out;

  dim3 blk(256);
  k_tc<<<dim3(32, 8, 4), blk, 0, stream>>>(x1, ht1, C, N);
  k_tc<<<dim3(32, 8, 4), blk, 0, stream>>>(x2, ht2, C, N);
  WT6 wt;
  wt.src[0] = Wq;  wt.dst[0] = wqt;
  wt.src[1] = Wk;  wt.dst[1] = wkt;
  wt.src[2] = Wv1; wt.dst[2] = wv1t;
  wt.src[3] = Wv2; wt.dst[3] = wv2t;
  wt.src[4] = Wo1; wt.dst[4] = wo1t;
  wt.src[5] = Wo2; wt.dst[5] = wo2t;
  k_tcw<<<dim3(8, 8, 6), blk, 0, stream>>>(wt);

  dim3 gg(BN / 128, C / 128);
  // q pre-scaled by 0.125*log2(e); k unscaled
  k_gemm<<<gg, blk, 0, stream>>>(ht1, wqt, bq, 0, SM_C, nullptr, qb, nullptr, nullptr);
  k_gemm<<<gg, blk, 0, stream>>>(ht2, wkt, bk, 0, 1.0f, nullptr, kb, nullptr, nullptr);

  dim3 gs(N / 128, Bsz * H);
  // qrs[q] = 1/sum_k exp2(S*c) ; krs[k] = 1/sum_q exp2(S*c)
  k_stats<<<gs, blk, 0, stream>>>(qb, kb, qrs);
  k_stats<<<gs, blk, 0, stream>>>(kb, qb, krs);

  // V projections with 1/sum folded in per token: v1 scaled by krs, v2 by qrs
  k_gemm<<<gg, blk, 0, stream>>>(ht1, wv1t, bv1, 1, 0.f, krs, vt1, nullptr, nullptr);
  k_gemm<<<gg, blk, 0, stream>>>(ht2, wv2t, bv2, 1, 0.f, qrs, vt2, nullptr, nullptr);

  // ctx1[q,d] = sum_k exp2(Sc[q,k]) * v1'[k,d]; ctx2[k,d] = sum_q exp2(Sc[q,k]) * v2'[q,d]
  k_ctx<<<gs, blk, 0, stream>>>(qb, kb, vt1, ctx1);
  k_ctx<<<gs, blk, 0, stream>>>(kb, qb, vt2, ctx2);

  k_gemm<<<gg, blk, 0, stream>>>(ctx1, wo1t, bo1, 2, 0.f, nullptr, nullptr, outf, x1);
  k_gemm<<<gg, blk, 0, stream>>>(ctx2, wo2t, bo2, 2, 0.f, nullptr, nullptr, outf + BCN, x2);
}

// Round 4
// 259.499 us; speedup vs baseline: 3.1650x; 1.0099x over previous
//
#include <hip/hip_runtime.h>

typedef __attribute__((ext_vector_type(8))) __bf16 bf16x8;
typedef __attribute__((ext_vector_type(4))) __bf16 bf16x4;
typedef __attribute__((ext_vector_type(4))) float f32x4;
typedef __attribute__((ext_vector_type(16))) float f32x16;
typedef unsigned int u32;

#define MFMA16(a, b, c) __builtin_amdgcn_mfma_f32_16x16x32_bf16((a), (b), (c), 0, 0, 0)
#define MFMA32(a, b, c) __builtin_amdgcn_mfma_f32_32x32x16_bf16((a), (b), (c), 0, 0, 0)
#define EXP2(x) __builtin_amdgcn_exp2f(x)

static constexpr int Bsz = 4, C = 512, N = 2048, H = 8, DH = 64;
static constexpr int BN = Bsz * N;
static constexpr size_t BCN = (size_t)Bsz * C * N;
static constexpr float SM_C = 0.18033688011112042f;  // 0.125 * log2(e)

// async global->LDS, 16B per lane; lds dest: wave-uniform base + lane*16
__device__ __forceinline__ void gload16(const void* g, void* lds) {
  __builtin_amdgcn_global_load_lds(
      (const __attribute__((address_space(1))) u32*)g,
      (__attribute__((address_space(3))) u32*)lds, 16, 0, 0);
}

// packed f32x2 -> bf16x2 (RNE)
__device__ __forceinline__ u32 cvt_pk_bf16(float lo, float hi) {
  u32 r;
  asm("v_cvt_pk_bf16_f32 %0, %1, %2" : "=v"(r) : "v"(lo), "v"(hi));
  return r;
}

// in-place: a' = {a_lo, b_lo}, b' = {a_hi, b_hi} (halves = lanes 0-31 / 32-63)
__device__ __forceinline__ void permswap32(u32& a, u32& b) {
  asm volatile("v_permlane32_swap_b32 %0, %1" : "+v"(a), "+v"(b));
}

// ---------------- workspace layout ----------------
static constexpr size_t SZ_BF = (size_t)BN * C * sizeof(__bf16);
static constexpr size_t SZ_W  = (size_t)C * C * sizeof(__bf16);
static constexpr size_t SZ_ST = (size_t)Bsz * H * N * sizeof(float);
static constexpr size_t OFF_HT1  = 0;
static constexpr size_t OFF_HT2  = OFF_HT1 + SZ_BF;
static constexpr size_t OFF_Q    = OFF_HT2 + SZ_BF;
static constexpr size_t OFF_K    = OFF_Q + SZ_BF;
static constexpr size_t OFF_VT1  = OFF_K + SZ_BF;    // v1^T (pre-scaled): [bh][d][N]
static constexpr size_t OFF_VT2  = OFF_VT1 + SZ_BF;
static constexpr size_t OFF_CTX1 = OFF_VT2 + SZ_BF;
static constexpr size_t OFF_CTX2 = OFF_CTX1 + SZ_BF;
static constexpr size_t OFF_WQT  = OFF_CTX2 + SZ_BF;
static constexpr size_t OFF_WKT  = OFF_WQT + SZ_W;
static constexpr size_t OFF_WV1T = OFF_WKT + SZ_W;
static constexpr size_t OFF_WV2T = OFF_WV1T + SZ_W;
static constexpr size_t OFF_WO1T = OFF_WV2T + SZ_W;
static constexpr size_t OFF_WO2T = OFF_WO1T + SZ_W;
static constexpr size_t OFF_QRS  = OFF_WO2T + SZ_W;  // per-q: 1/sum_k exp2(S*c)
static constexpr size_t OFF_KRS  = OFF_QRS + SZ_ST;  // per-k: 1/sum_q exp2(S*c)

// ---------------- fp32 -> bf16 tiled transpose (x inputs) ----------------
__global__ __launch_bounds__(256) void k_tc(const float* __restrict__ src,
                                            __bf16* __restrict__ dst, int R, int S) {
  __shared__ __bf16 tile[64][66];
  size_t boff = (size_t)blockIdx.z * R * S;
  src += boff;
  dst += boff;
  int r0 = blockIdx.y * 64, c0 = blockIdx.x * 64;
  int t = threadIdx.x;
  int cl = t & 63, rr = t >> 6;
#pragma unroll
  for (int i = 0; i < 16; ++i) {
    int r = rr * 16 + i;
    tile[r][cl] = (__bf16)src[(size_t)(r0 + r) * S + c0 + cl];
  }
  __syncthreads();
#pragma unroll
  for (int i = 0; i < 16; ++i) {
    int c = rr * 16 + i;
    dst[(size_t)(c0 + c) * R + r0 + cl] = tile[cl][c];
  }
}

// all six 512x512 weight transposes in one dispatch (z = which weight)
struct WT6 {
  const float* src[6];
  __bf16* dst[6];
};
__global__ __launch_bounds__(256) void k_tcw(WT6 p) {
  __shared__ __bf16 tile[64][66];
  int z = blockIdx.z;
  const float* src = p.src[z];
  __bf16* dst = p.dst[z];
  int r0 = blockIdx.y * 64, c0 = blockIdx.x * 64;
  int t = threadIdx.x;
  int cl = t & 63, rr = t >> 6;
#pragma unroll
  for (int i = 0; i < 16; ++i) {
    int r = rr * 16 + i;
    tile[r][cl] = (__bf16)src[(size_t)(r0 + r) * C + c0 + cl];
  }
  __syncthreads();
#pragma unroll
  for (int i = 0; i < 16; ++i) {
    int c = rr * 16 + i;
    dst[(size_t)(c0 + c) * C + r0 + cl] = tile[cl][c];
  }
}

// ---------------- GEMM (m97 structure): 128x128 tile, BK=32 ----------------
// mode 0: bf16 q/k layout [bh][n][64], out = (acc+bias)*scale
// mode 1: bf16 v^T layout [bh][d][N], out = (acc+bias)*rs[bh][token]
// mode 2: fp32 [b][col][n] + residual
__global__ __launch_bounds__(256) void k_gemm(
    const __bf16* __restrict__ A, const __bf16* __restrict__ Bt,
    const float* __restrict__ bias, int mode, float scale,
    const float* __restrict__ rs,
    __bf16* __restrict__ outb, float* __restrict__ outf,
    const float* __restrict__ resid) {
  __shared__ __bf16 As[128 * 32];
  __shared__ __bf16 Bs[128 * 32];
  // XCD swizzle: 256 blocks, 8 XCDs -> 32 consecutive per XCD
  int lin = blockIdx.y * 64 + blockIdx.x;
  int swz = (lin & 7) * 32 + (lin >> 3);
  int m0 = (swz & 63) * 128, n0 = (swz >> 6) * 128;
  int t = threadIdx.x, lane = t & 63, w = t >> 6;
  int wm = w >> 1, wn = w & 1;
  int l15 = lane & 15, l4 = lane >> 4;
  int srow = t >> 2;
  int scol = (t & 3) * 8;
  char* abase0 = (char*)As + w * 1024;
  char* abase1 = (char*)As + 4096 + w * 1024;
  char* bbase0 = (char*)Bs + w * 1024;
  char* bbase1 = (char*)Bs + 4096 + w * 1024;
  f32x4 acc[4][4] = {};
  for (int k0 = 0; k0 < C; k0 += 32) {
    gload16(&A[(size_t)(m0 + srow) * C + k0 + scol], abase0);
    gload16(&A[(size_t)(m0 + 64 + srow) * C + k0 + scol], abase1);
    gload16(&Bt[(size_t)(n0 + srow) * C + k0 + scol], bbase0);
    gload16(&Bt[(size_t)(n0 + 64 + srow) * C + k0 + scol], bbase1);
    __syncthreads();
    bf16x8 af[4], bfr[4];
#pragma unroll
    for (int i = 0; i < 4; ++i)
      af[i] = *(const bf16x8*)&As[(wm * 64 + i * 16 + l15) * 32 + l4 * 8];
#pragma unroll
    for (int i = 0; i < 4; ++i)
      bfr[i] = *(const bf16x8*)&Bs[(wn * 64 + i * 16 + l15) * 32 + l4 * 8];
#pragma unroll
    for (int mi = 0; mi < 4; ++mi)
#pragma unroll
      for (int ni = 0; ni < 4; ++ni)
        acc[mi][ni] = MFMA16(af[mi], bfr[ni], acc[mi][ni]);
    __syncthreads();
  }
#pragma unroll
  for (int mi = 0; mi < 4; ++mi)
#pragma unroll
    for (int ni = 0; ni < 4; ++ni) {
      int gm = m0 + wm * 64 + mi * 16 + l4 * 4;  // token rows gm..gm+3
      int gn = n0 + wn * 64 + ni * 16 + l15;     // output channel
      float bv = bias[gn];
      f32x4 v = acc[mi][ni];
      int b = gm >> 11, n = gm & 2047;
      if (mode == 0) {
        int h = gn >> 6, d = gn & 63;
        size_t base = (size_t)(b * 8 + h) * 2048 + n;
#pragma unroll
        for (int j = 0; j < 4; ++j)
          outb[(base + j) * 64 + d] = (__bf16)((v[j] + bv) * scale);
      } else if (mode == 1) {
        int h = gn >> 6, d = gn & 63;
        size_t tok = (size_t)(b * 8 + h) * 2048 + n;
        float4 rv = *reinterpret_cast<const float4*>(&rs[tok]);
        size_t addr = ((size_t)(b * 8 + h) * 64 + d) * 2048 + n;
        union { __bf16 h4[4]; uint2 u; } pk;
        pk.h4[0] = (__bf16)((v[0] + bv) * rv.x);
        pk.h4[1] = (__bf16)((v[1] + bv) * rv.y);
        pk.h4[2] = (__bf16)((v[2] + bv) * rv.z);
        pk.h4[3] = (__bf16)((v[3] + bv) * rv.w);
        *reinterpret_cast<uint2*>(&outb[addr]) = pk.u;
      } else {
        size_t addr = ((size_t)b * C + gn) * 2048 + n;
        float4 xv = *reinterpret_cast<const float4*>(&resid[addr]);
        float4 ov;
        ov.x = v[0] + bv + xv.x;
        ov.y = v[1] + bv + xv.y;
        ov.z = v[2] + bv + xv.z;
        ov.w = v[3] + bv + xv.w;
        *reinterpret_cast<float4*>(&outf[addr]) = ov;
      }
    }
}

// ---------------- stats (32x32 MFMA): 1/sum over Y-rows of exp2(S) -------
// S^T = mfma32(Y, X): D[col=q=lane&31][row=c]. In-lane sum + shfl_xor(32).
__global__ __launch_bounds__(256, 4) void k_stats(
    const __bf16* __restrict__ X, const __bf16* __restrict__ Y,
    float* __restrict__ ors) {
  __shared__ __bf16 Ys[64 * 64];
  int lin = blockIdx.y * gridDim.x + blockIdx.x;  // 512 blocks
  int swz = (lin & 7) * 64 + (lin >> 3);
  int bh = swz >> 4, xblk = swz & 15;
  int t = threadIdx.x, lane = t & 63, w = t >> 6;
  int l31 = lane & 31, hi = lane >> 5;
  const __bf16* Xb = X + (size_t)bh * N * DH;
  const __bf16* Yb = Y + (size_t)bh * N * DH;
  int qg = xblk * 128 + w * 32 + l31;
  bf16x8 xq[4];
#pragma unroll
  for (int kk = 0; kk < 4; ++kk)
    xq[kk] = *(const bf16x8*)&Xb[(size_t)qg * DH + kk * 16 + hi * 8];
  int srow = t >> 3;
  int sc8 = ((t & 7) ^ (srow & 7)) * 8;
  char* yd0 = (char*)Ys + w * 1024;
  char* yd1 = (char*)Ys + 4096 + w * 1024;
  float ssum = 0.f;
  for (int kc = 0; kc < N; kc += 64) {
    gload16(&Yb[(size_t)(kc + srow) * DH + sc8], yd0);
    gload16(&Yb[(size_t)(kc + 32 + srow) * DH + sc8], yd1);
    __syncthreads();
#pragma unroll
    for (int cblk = 0; cblk < 2; ++cblk) {
      f32x16 sacc = {};
      int row = cblk * 32 + l31;
      int sw = (row & 7) << 4;
#pragma unroll
      for (int kk = 0; kk < 4; ++kk) {
        bf16x8 yf = *(const bf16x8*)((const char*)Ys + row * 128 + ((kk * 32 + hi * 16) ^ sw));
        sacc = MFMA32(yf, xq[kk], sacc);
      }
#pragma unroll
      for (int e = 0; e < 16; ++e) ssum += EXP2(sacc[e]);
    }
    __syncthreads();
  }
  ssum += __shfl_xor(ssum, 32, 64);
  if (hi == 0) ors[(size_t)bh * N + qg] = 1.0f / ssum;
}

// ---------------- ctx (32x32 MFMA, P stays in registers) ----------------
// S^T = mfma32(Y, X); P-fragment for PV built via cvt_pk + permlane32_swap;
// PV = mfma32(V, P) -> D[col=q][row=d], packed b64 stores.
__global__ __launch_bounds__(256, 2) void k_ctx(
    const __bf16* __restrict__ X, const __bf16* __restrict__ Y,
    const __bf16* __restrict__ Vt, __bf16* __restrict__ out) {
  __shared__ __bf16 Ys[64 * 64];
  __shared__ __bf16 Vs[64 * 64];
  int lin = blockIdx.y * gridDim.x + blockIdx.x;  // 512 blocks
  int swz = (lin & 7) * 64 + (lin >> 3);
  int bh = swz >> 4, xblk = swz & 15;
  int b = bh >> 3, h = bh & 7;
  int t = threadIdx.x, lane = t & 63, w = t >> 6;
  int l31 = lane & 31, hi = lane >> 5;
  const __bf16* Xb = X + (size_t)bh * N * DH;
  const __bf16* Yb = Y + (size_t)bh * N * DH;
  const __bf16* Vb = Vt + (size_t)bh * DH * N;
  int qg = xblk * 128 + w * 32 + l31;
  bf16x8 xq[4];
#pragma unroll
  for (int kk = 0; kk < 4; ++kk)
    xq[kk] = *(const bf16x8*)&Xb[(size_t)qg * DH + kk * 16 + hi * 8];
  int srow = t >> 3;
  int sc8 = ((t & 7) ^ (srow & 7)) * 8;
  char* yd0 = (char*)Ys + w * 1024;
  char* yd1 = (char*)Ys + 4096 + w * 1024;
  char* vd0 = (char*)Vs + w * 1024;
  char* vd1 = (char*)Vs + 4096 + w * 1024;
  f32x16 oacc[2] = {};
  for (int kc = 0; kc < N; kc += 64) {
    gload16(&Yb[(size_t)(kc + srow) * DH + sc8], yd0);
    gload16(&Yb[(size_t)(kc + 32 + srow) * DH + sc8], yd1);
    gload16(&Vb[(size_t)srow * N + kc + sc8], vd0);
    gload16(&Vb[(size_t)(32 + srow) * N + kc + sc8], vd1);
    __syncthreads();
    // ---- S^T: 8 MFMA (2 c-blocks x K=64) ----
    f32x16 sacc[2] = {};
#pragma unroll
    for (int cblk = 0; cblk < 2; ++cblk) {
      int row = cblk * 32 + l31;
      int sw = (row & 7) << 4;
#pragma unroll
      for (int kk = 0; kk < 4; ++kk) {
        bf16x8 yf = *(const bf16x8*)((const char*)Ys + row * 128 + ((kk * 32 + hi * 16) ^ sw));
        sacc[cblk] = MFMA32(yf, xq[kk], sacc[cblk]);
      }
    }
    // ---- P = exp2(S) packed to bf16 words; c_local = 8g + 4hi + {0..3} ----
    u32 wl[2][4], wh[2][4];
#pragma unroll
    for (int cblk = 0; cblk < 2; ++cblk)
#pragma unroll
      for (int g = 0; g < 4; ++g) {
        float e0 = EXP2(sacc[cblk][4 * g + 0]);
        float e1 = EXP2(sacc[cblk][4 * g + 1]);
        float e2 = EXP2(sacc[cblk][4 * g + 2]);
        float e3 = EXP2(sacc[cblk][4 * g + 3]);
        wl[cblk][g] = cvt_pk_bf16(e0, e1);
        wh[cblk][g] = cvt_pk_bf16(e2, e3);
      }
    // ---- PV: 4 K=16 chunks; B-frag assembled by 2 permlane32_swap each ----
#pragma unroll
    for (int ct = 0; ct < 4; ++ct) {
      int cblk = ct >> 1, s = ct & 1;
      u32 a0 = wl[cblk][2 * s], b0 = wl[cblk][2 * s + 1];
      u32 a1 = wh[cblk][2 * s], b1 = wh[cblk][2 * s + 1];
      permswap32(a0, b0);  // a0 = bw0, b0 = bw2
      permswap32(a1, b1);  // a1 = bw1, b1 = bw3
      union { u32 wd[4]; bf16x8 v; } pf;
      pf.wd[0] = a0; pf.wd[1] = a1; pf.wd[2] = b0; pf.wd[3] = b1;
#pragma unroll
      for (int dblk = 0; dblk < 2; ++dblk) {
        int vrow = dblk * 32 + l31;
        int vw = (vrow & 7) << 4;
        bf16x8 vf = *(const bf16x8*)((const char*)Vs + vrow * 128 + ((ct * 32 + hi * 16) ^ vw));
        oacc[dblk] = MFMA32(vf, pf.v, oacc[dblk]);
      }
    }
    __syncthreads();
  }
  // ---- store: lane q=qg, d = dblk*32 + 8g + 4hi + m ----
#pragma unroll
  for (int dblk = 0; dblk < 2; ++dblk)
#pragma unroll
    for (int g = 0; g < 4; ++g) {
      union { __bf16 h4[4]; uint2 u; } pk;
#pragma unroll
      for (int m = 0; m < 4; ++m) pk.h4[m] = (__bf16)oacc[dblk][4 * g + m];
      int d = dblk * 32 + 8 * g + 4 * hi;
      size_t addr = ((size_t)b * N + qg) * C + h * 64 + d;
      *reinterpret_cast<uint2*>(&out[addr]) = pk.u;
    }
}

extern "C" void kernel_launch(void* const* d_in, const int* in_sizes, int n_in,
                              void* d_out, int out_size, void* d_ws, size_t ws_size,
                              hipStream_t stream) {
  (void)in_sizes; (void)n_in; (void)out_size; (void)ws_size;
  const float* x1  = (const float*)d_in[0];
  const float* x2  = (const float*)d_in[1];
  const float* Wq  = (const float*)d_in[2];
  const float* bq  = (const float*)d_in[3];
  const float* Wk  = (const float*)d_in[4];
  const float* bk  = (const float*)d_in[5];
  const float* Wv1 = (const float*)d_in[6];
  const float* bv1 = (const float*)d_in[7];
  const float* Wv2 = (const float*)d_in[8];
  const float* bv2 = (const float*)d_in[9];
  const float* Wo1 = (const float*)d_in[10];
  const float* bo1 = (const float*)d_in[11];
  const float* Wo2 = (const float*)d_in[12];
  const float* bo2 = (const float*)d_in[13];

  char* ws = (char*)d_ws;
  __bf16* ht1  = (__bf16*)(ws + OFF_HT1);
  __bf16* ht2  = (__bf16*)(ws + OFF_HT2);
  __bf16* qb   = (__bf16*)(ws + OFF_Q);
  __bf16* kb   = (__bf16*)(ws + OFF_K);
  __bf16* vt1  = (__bf16*)(ws + OFF_VT1);
  __bf16* vt2  = (__bf16*)(ws + OFF_VT2);
  __bf16* ctx1 = (__bf16*)(ws + OFF_CTX1);
  __bf16* ctx2 = (__bf16*)(ws + OFF_CTX2);
  __bf16* wqt  = (__bf16*)(ws + OFF_WQT);
  __bf16* wkt  = (__bf16*)(ws + OFF_WKT);
  __bf16* wv1t = (__bf16*)(ws + OFF_WV1T);
  __bf16* wv2t = (__bf16*)(ws + OFF_WV2T);
  __bf16* wo1t = (__bf16*)(ws + OFF_WO1T);
  __bf16* wo2t = (__bf16*)(ws + OFF_WO2T);
  float* qrs = (float*)(ws + OFF_QRS);
  float* krs = (float*)(ws + OFF_KRS);
  float* outf = (float*)d_out;

  dim3 blk(256);
  k_tc<<<dim3(32, 8, 4), blk, 0, stream>>>(x1, ht1, C, N);
  k_tc<<<dim3(32, 8, 4), blk, 0, stream>>>(x2, ht2, C, N);
  WT6 wt;
  wt.src[0] = Wq;  wt.dst[0] = wqt;
  wt.src[1] = Wk;  wt.dst[1] = wkt;
  wt.src[2] = Wv1; wt.dst[2] = wv1t;
  wt.src[3] = Wv2; wt.dst[3] = wv2t;
  wt.src[4] = Wo1; wt.dst[4] = wo1t;
  wt.src[5] = Wo2; wt.dst[5] = wo2t;
  k_tcw<<<dim3(8, 8, 6), blk, 0, stream>>>(wt);

  dim3 gg(BN / 128, C / 128);
  // q pre-scaled by 0.125*log2(e); k unscaled
  k_gemm<<<gg, blk, 0, stream>>>(ht1, wqt, bq, 0, SM_C, nullptr, qb, nullptr, nullptr);
  k_gemm<<<gg, blk, 0, stream>>>(ht2, wkt, bk, 0, 1.0f, nullptr, kb, nullptr, nullptr);

  dim3 gs(N / 128, Bsz * H);
  // qrs[q] = 1/sum_k exp2(S*c) ; krs[k] = 1/sum_q exp2(S*c)
  k_stats<<<gs, blk, 0, stream>>>(qb, kb, qrs);
  k_stats<<<gs, blk, 0, stream>>>(kb, qb, krs);

  // V projections with 1/sum folded in per token: v1 scaled by krs, v2 by qrs
  k_gemm<<<gg, blk, 0, stream>>>(ht1, wv1t, bv1, 1, 0.f, krs, vt1, nullptr, nullptr);
  k_gemm<<<gg, blk, 0, stream>>>(ht2, wv2t, bv2, 1, 0.f, qrs, vt2, nullptr, nullptr);

  // ctx1[q,d] = sum_k exp2(Sc[q,k]) * v1'[k,d]; ctx2[k,d] = sum_q exp2(Sc[q,k]) * v2'[q,d]
  k_ctx<<<gs, blk, 0, stream>>>(qb, kb, vt1, ctx1);
  k_ctx<<<gs, blk, 0, stream>>>(kb, qb, vt2, ctx2);

  k_gemm<<<gg, blk, 0, stream>>>(ctx1, wo1t, bo1, 2, 0.f, nullptr, nullptr, outf, x1);
  k_gemm<<<gg, blk, 0, stream>>>(ctx2, wo2t, bo2, 2, 0.f, nullptr, nullptr, outf + BCN, x2);
}

// Round 5
// 192.852 us; speedup vs baseline: 4.2587x; 1.3456x over previous
//
#include <hip/hip_runtime.h>

typedef __attribute__((ext_vector_type(8))) __bf16 bf16x8;
typedef __attribute__((ext_vector_type(4))) float f32x4;
typedef __attribute__((ext_vector_type(16))) float f32x16;
typedef unsigned int u32;

#define MFMA32(a, b, c) __builtin_amdgcn_mfma_f32_32x32x16_bf16((a), (b), (c), 0, 0, 0)
#define EXP2(x) __builtin_amdgcn_exp2f(x)

static constexpr int Bsz = 4, C = 512, N = 2048, H = 8, DH = 64;
static constexpr int BN = Bsz * N;
static constexpr size_t BCN = (size_t)Bsz * C * N;
static constexpr float SM_C = 0.18033688011112042f;  // 0.125 * log2(e)

// async global->LDS, 16B per lane; lds dest: wave-uniform base + lane*16
__device__ __forceinline__ void gload16(const void* g, void* lds) {
  __builtin_amdgcn_global_load_lds(
      (const __attribute__((address_space(1))) u32*)g,
      (__attribute__((address_space(3))) u32*)lds, 16, 0, 0);
}

// packed f32x2 -> bf16x2 (RNE)
__device__ __forceinline__ u32 cvt_pk_bf16(float lo, float hi) {
  u32 r;
  asm("v_cvt_pk_bf16_f32 %0, %1, %2" : "=v"(r) : "v"(lo), "v"(hi));
  return r;
}

// in-place: a' = {a_lo, b_lo}, b' = {a_hi, b_hi} (halves = lanes 0-31 / 32-63)
__device__ __forceinline__ void permswap32(u32& a, u32& b) {
  asm volatile("v_permlane32_swap_b32 %0, %1" : "+v"(a), "+v"(b));
}

// ---------------- workspace layout ----------------
static constexpr size_t SZ_BF = (size_t)BN * C * sizeof(__bf16);
static constexpr size_t SZ_W  = (size_t)C * C * sizeof(__bf16);
static constexpr size_t SZ_ST = (size_t)Bsz * H * N * sizeof(float);
static constexpr size_t OFF_HT1  = 0;
static constexpr size_t OFF_HT2  = OFF_HT1 + SZ_BF;
static constexpr size_t OFF_Q    = OFF_HT2 + SZ_BF;
static constexpr size_t OFF_K    = OFF_Q + SZ_BF;
static constexpr size_t OFF_VT1  = OFF_K + SZ_BF;    // v1^T (pre-scaled): [bh][d][N]
static constexpr size_t OFF_VT2  = OFF_VT1 + SZ_BF;
static constexpr size_t OFF_CTX1 = OFF_VT2 + SZ_BF;
static constexpr size_t OFF_CTX2 = OFF_CTX1 + SZ_BF;
static constexpr size_t OFF_WQT  = OFF_CTX2 + SZ_BF;
static constexpr size_t OFF_WKT  = OFF_WQT + SZ_W;
static constexpr size_t OFF_WV1T = OFF_WKT + SZ_W;
static constexpr size_t OFF_WV2T = OFF_WV1T + SZ_W;
static constexpr size_t OFF_WO1T = OFF_WV2T + SZ_W;
static constexpr size_t OFF_WO2T = OFF_WO1T + SZ_W;
static constexpr size_t OFF_QRS  = OFF_WO2T + SZ_W;  // per-q: 1/sum_k exp2(S*c)
static constexpr size_t OFF_KRS  = OFF_QRS + SZ_ST;  // per-k: 1/sum_q exp2(S*c)

// ---------------- fp32 -> bf16 tiled transpose: both x inputs, z=0..7 -------
__global__ __launch_bounds__(256) void k_tc2(const float* __restrict__ x1,
                                             const float* __restrict__ x2,
                                             __bf16* __restrict__ h1,
                                             __bf16* __restrict__ h2) {
  __shared__ __bf16 tile[64][66];
  int z = blockIdx.z;
  size_t boff = (size_t)(z & 3) * C * N;
  const float* src = (z < 4 ? x1 : x2) + boff;
  __bf16* dst = (z < 4 ? h1 : h2) + boff;
  int r0 = blockIdx.y * 64, c0 = blockIdx.x * 64;
  int t = threadIdx.x;
  int cl = t & 63, rr = t >> 6;
#pragma unroll
  for (int i = 0; i < 16; ++i) {
    int r = rr * 16 + i;
    tile[r][cl] = (__bf16)src[(size_t)(r0 + r) * N + c0 + cl];
  }
  __syncthreads();
#pragma unroll
  for (int i = 0; i < 16; ++i) {
    int c = rr * 16 + i;
    dst[(size_t)(c0 + c) * C + r0 + cl] = tile[cl][c];
  }
}

// all six 512x512 weight transposes in one dispatch (z = which weight)
struct WT6 {
  const float* src[6];
  __bf16* dst[6];
};
__global__ __launch_bounds__(256) void k_tcw(WT6 p) {
  __shared__ __bf16 tile[64][66];
  int z = blockIdx.z;
  const float* src = p.src[z];
  __bf16* dst = p.dst[z];
  int r0 = blockIdx.y * 64, c0 = blockIdx.x * 64;
  int t = threadIdx.x;
  int cl = t & 63, rr = t >> 6;
#pragma unroll
  for (int i = 0; i < 16; ++i) {
    int r = rr * 16 + i;
    tile[r][cl] = (__bf16)src[(size_t)(r0 + r) * C + c0 + cl];
  }
  __syncthreads();
#pragma unroll
  for (int i = 0; i < 16; ++i) {
    int c = rr * 16 + i;
    dst[(size_t)(c0 + c) * C + r0 + cl] = tile[cl][c];
  }
}

// ---------------- GEMM: 128x128 tile, BK=64, MFMA32, dbuf+prefetch ----------
// two directions per dispatch (512 blocks). out = A(8192x512) @ Bt^T + bias
// MODE 0: bf16 q/k layout [bh][n][64], out = (acc+bias)*scale
// MODE 1: bf16 v^T layout [bh][d][N], out = (acc+bias)*rs[bh][token]
// MODE 2: fp32 [b][col][n] + residual
struct GArgs {
  const __bf16* A; const __bf16* Bt; const float* bias; const float* rs;
  __bf16* outb; float* outf; const float* resid; float scale;
};

template <int MODE>
__global__ __launch_bounds__(256, 2) void k_gemm(GArgs g0, GArgs g1) {
  __shared__ __bf16 As[2 * 128 * 64];
  __shared__ __bf16 Bs[2 * 128 * 64];
  int lin = blockIdx.x;  // 0..511
  int swz = (lin & 7) * 64 + (lin >> 3);
  int dir = swz >> 8;
  int inner = swz & 255;
  const __bf16* Ap = dir ? g1.A : g0.A;
  const __bf16* Bp = dir ? g1.Bt : g0.Bt;
  const float* bias = dir ? g1.bias : g0.bias;
  const float* rs = dir ? g1.rs : g0.rs;
  __bf16* outb = dir ? g1.outb : g0.outb;
  float* outf = dir ? g1.outf : g0.outf;
  const float* resid = dir ? g1.resid : g0.resid;
  float scale = dir ? g1.scale : g0.scale;
  int m0 = (inner & 63) * 128, n0 = (inner >> 6) * 128;
  int t = threadIdx.x, lane = t & 63, w = t >> 6;
  int wm = w >> 1, wn = w & 1;
  int l31 = lane & 31, hi = lane >> 5;
  int srow = t >> 3;
  int sc8 = ((t & 7) ^ (srow & 7)) * 8;  // pre-swizzled source col (elems)
  int swA = (l31 & 7) << 4;
  f32x16 acc[2][2] = {};

#define GSTAGE(p, k0)                                                        \
  {                                                                          \
    _Pragma("unroll") for (int gI = 0; gI < 4; ++gI) {                       \
      int row_ = gI * 32 + srow;                                             \
      gload16(&Ap[(size_t)(m0 + row_) * C + (k0) + sc8],                     \
              (char*)As + (p) * 16384 + gI * 4096 + w * 1024);               \
      gload16(&Bp[(size_t)(n0 + row_) * C + (k0) + sc8],                     \
              (char*)Bs + (p) * 16384 + gI * 4096 + w * 1024);               \
    }                                                                        \
  }

  GSTAGE(0, 0)
  __syncthreads();
  for (int ks = 0; ks < 8; ++ks) {
    int p = ks & 1;
    if (ks < 7) GSTAGE(p ^ 1, (ks + 1) * 64)
    const char* ab = (const char*)As + p * 16384;
    const char* bb = (const char*)Bs + p * 16384;
#pragma unroll
    for (int kk = 0; kk < 4; ++kk) {
      int ko = (kk * 32 + hi * 16);
      bf16x8 a0 = *(const bf16x8*)(ab + (wm * 64 + l31) * 128 + (ko ^ swA));
      bf16x8 a1 = *(const bf16x8*)(ab + (wm * 64 + 32 + l31) * 128 + (ko ^ swA));
      bf16x8 b0 = *(const bf16x8*)(bb + (wn * 64 + l31) * 128 + (ko ^ swA));
      bf16x8 b1 = *(const bf16x8*)(bb + (wn * 64 + 32 + l31) * 128 + (ko ^ swA));
      acc[0][0] = MFMA32(a0, b0, acc[0][0]);
      acc[0][1] = MFMA32(a0, b1, acc[0][1]);
      acc[1][0] = MFMA32(a1, b0, acc[1][0]);
      acc[1][1] = MFMA32(a1, b1, acc[1][1]);
    }
    __syncthreads();
  }
#pragma unroll
  for (int mi = 0; mi < 2; ++mi)
#pragma unroll
    for (int ni = 0; ni < 2; ++ni) {
      int gn = n0 + wn * 64 + ni * 32 + l31;
      float bv = bias[gn];
#pragma unroll
      for (int g2 = 0; g2 < 4; ++g2) {
        int gm = m0 + wm * 64 + mi * 32 + 8 * g2 + 4 * hi;  // 4 consecutive tokens
        int b = gm >> 11, n = gm & 2047;
        if (MODE == 0) {
          int h = gn >> 6, d = gn & 63;
          size_t base = (size_t)(b * 8 + h) * 2048 + n;
#pragma unroll
          for (int j = 0; j < 4; ++j)
            outb[(base + j) * 64 + d] = (__bf16)((acc[mi][ni][4 * g2 + j] + bv) * scale);
        } else if (MODE == 1) {
          int h = gn >> 6, d = gn & 63;
          size_t tok = (size_t)(b * 8 + h) * 2048 + n;
          float4 rv = *reinterpret_cast<const float4*>(&rs[tok]);
          size_t addr = ((size_t)(b * 8 + h) * 64 + d) * 2048 + n;
          union { __bf16 h4[4]; uint2 u; } pk;
          pk.h4[0] = (__bf16)((acc[mi][ni][4 * g2 + 0] + bv) * rv.x);
          pk.h4[1] = (__bf16)((acc[mi][ni][4 * g2 + 1] + bv) * rv.y);
          pk.h4[2] = (__bf16)((acc[mi][ni][4 * g2 + 2] + bv) * rv.z);
          pk.h4[3] = (__bf16)((acc[mi][ni][4 * g2 + 3] + bv) * rv.w);
          *reinterpret_cast<uint2*>(&outb[addr]) = pk.u;
        } else {
          size_t addr = ((size_t)b * C + gn) * 2048 + n;
          float4 xv = *reinterpret_cast<const float4*>(&resid[addr]);
          float4 ov;
          ov.x = acc[mi][ni][4 * g2 + 0] + bv + xv.x;
          ov.y = acc[mi][ni][4 * g2 + 1] + bv + xv.y;
          ov.z = acc[mi][ni][4 * g2 + 2] + bv + xv.z;
          ov.w = acc[mi][ni][4 * g2 + 3] + bv + xv.w;
          *reinterpret_cast<float4*>(&outf[addr]) = ov;
        }
      }
    }
}

// ---------------- stats: 1/sum over Y-rows of exp2(S), 64 q/wave ------------
struct SArgs { const __bf16* X; const __bf16* Y; float* ors; };

__global__ __launch_bounds__(256, 2) void k_stats(SArgs sa0, SArgs sa1) {
  __shared__ __bf16 Ys[2 * 64 * 64];
  int lin = blockIdx.x;  // 0..511
  int swz = (lin & 7) * 64 + (lin >> 3);
  int dir = swz >> 8;
  int inner = swz & 255;
  const __bf16* X = dir ? sa1.X : sa0.X;
  const __bf16* Y = dir ? sa1.Y : sa0.Y;
  float* ors = dir ? sa1.ors : sa0.ors;
  int bh = inner >> 3, xblk = inner & 7;
  int t = threadIdx.x, lane = t & 63, w = t >> 6;
  int l31 = lane & 31, hi = lane >> 5;
  const __bf16* Xb = X + (size_t)bh * N * DH;
  const __bf16* Yb = Y + (size_t)bh * N * DH;
  int qg = xblk * 256 + w * 64 + l31;
  bf16x8 xq[2][4];
#pragma unroll
  for (int s = 0; s < 2; ++s)
#pragma unroll
    for (int kk = 0; kk < 4; ++kk)
      xq[s][kk] = *(const bf16x8*)&Xb[(size_t)(qg + s * 32) * DH + kk * 16 + hi * 8];
  int srow = t >> 3;
  int sc8 = ((t & 7) ^ (srow & 7)) * 8;
#define SSTAGE(p, kc2)                                                       \
  {                                                                          \
    char* yb_ = (char*)Ys + (p) * 8192 + w * 1024;                           \
    gload16(&Yb[(size_t)((kc2) + srow) * DH + sc8], yb_);                    \
    gload16(&Yb[(size_t)((kc2) + 32 + srow) * DH + sc8], yb_ + 4096);        \
  }
  float sum0 = 0.f, sum1 = 0.f;
  SSTAGE(0, 0)
  __syncthreads();
  for (int it = 0; it < 32; ++it) {
    int p = it & 1;
    if (it < 31) SSTAGE(p ^ 1, (it + 1) * 64)
    const char* yb = (const char*)Ys + p * 8192;
#pragma unroll
    for (int cblk = 0; cblk < 2; ++cblk) {
      f32x16 s0 = {}, s1 = {};
      int row = cblk * 32 + l31;
      int sw = (row & 7) << 4;
#pragma unroll
      for (int kk = 0; kk < 4; ++kk) {
        bf16x8 yf = *(const bf16x8*)(yb + row * 128 + ((kk * 32 + hi * 16) ^ sw));
        s0 = MFMA32(yf, xq[0][kk], s0);
        s1 = MFMA32(yf, xq[1][kk], s1);
      }
#pragma unroll
      for (int e = 0; e < 16; ++e) {
        sum0 += EXP2(s0[e]);
        sum1 += EXP2(s1[e]);
      }
    }
    __syncthreads();
  }
  sum0 += __shfl_xor(sum0, 32, 64);
  sum1 += __shfl_xor(sum1, 32, 64);
  if (hi == 0) {
    ors[(size_t)bh * N + qg] = 1.0f / sum0;
    ors[(size_t)bh * N + qg + 32] = 1.0f / sum1;
  }
}

// ---------------- ctx: out[q,d] = sum_c exp2(S[q,c]) * V'[c,d], 64 q/wave ---
struct CArgs { const __bf16* X; const __bf16* Y; const __bf16* Vt; __bf16* out; };

__global__ __launch_bounds__(256, 2) void k_ctx(CArgs c0, CArgs c1) {
  __shared__ __bf16 Ys[2 * 64 * 64];
  __shared__ __bf16 Vs[2 * 64 * 64];
  int lin = blockIdx.x;  // 0..511
  int swz = (lin & 7) * 64 + (lin >> 3);
  int dir = swz >> 8;
  int inner = swz & 255;
  const __bf16* X = dir ? c1.X : c0.X;
  const __bf16* Y = dir ? c1.Y : c0.Y;
  const __bf16* Vt = dir ? c1.Vt : c0.Vt;
  __bf16* out = dir ? c1.out : c0.out;
  int bh = inner >> 3, xblk = inner & 7;
  int b = bh >> 3, h = bh & 7;
  int t = threadIdx.x, lane = t & 63, w = t >> 6;
  int l31 = lane & 31, hi = lane >> 5;
  const __bf16* Xb = X + (size_t)bh * N * DH;
  const __bf16* Yb = Y + (size_t)bh * N * DH;
  const __bf16* Vb = Vt + (size_t)bh * DH * N;
  int qg = xblk * 256 + w * 64 + l31;
  bf16x8 xq[2][4];
#pragma unroll
  for (int s = 0; s < 2; ++s)
#pragma unroll
    for (int kk = 0; kk < 4; ++kk)
      xq[s][kk] = *(const bf16x8*)&Xb[(size_t)(qg + s * 32) * DH + kk * 16 + hi * 8];
  int srow = t >> 3;
  int sc8 = ((t & 7) ^ (srow & 7)) * 8;
#define CSTAGE(p, kc2)                                                       \
  {                                                                          \
    char* yb_ = (char*)Ys + (p) * 8192 + w * 1024;                           \
    char* vb_ = (char*)Vs + (p) * 8192 + w * 1024;                           \
    gload16(&Yb[(size_t)((kc2) + srow) * DH + sc8], yb_);                    \
    gload16(&Yb[(size_t)((kc2) + 32 + srow) * DH + sc8], yb_ + 4096);        \
    gload16(&Vb[(size_t)srow * N + (kc2) + sc8], vb_);                       \
    gload16(&Vb[(size_t)(32 + srow) * N + (kc2) + sc8], vb_ + 4096);         \
  }
  f32x16 oacc[2][2] = {};
  CSTAGE(0, 0)
  __syncthreads();
  for (int it = 0; it < 32; ++it) {
    int p = it & 1;
    if (it < 31) CSTAGE(p ^ 1, (it + 1) * 64)
    const char* yb = (const char*)Ys + p * 8192;
    const char* vb = (const char*)Vs + p * 8192;
    // ---- S^T: 16 MFMA (2 sets x 2 cblk x K=64); P packed in-register ----
    u32 wl[2][2][4], wh[2][2][4];  // [set][cblk][g]
#pragma unroll
    for (int cblk = 0; cblk < 2; ++cblk) {
      f32x16 s0 = {}, s1 = {};
      int row = cblk * 32 + l31;
      int sw = (row & 7) << 4;
#pragma unroll
      for (int kk = 0; kk < 4; ++kk) {
        bf16x8 yf = *(const bf16x8*)(yb + row * 128 + ((kk * 32 + hi * 16) ^ sw));
        s0 = MFMA32(yf, xq[0][kk], s0);
        s1 = MFMA32(yf, xq[1][kk], s1);
      }
#pragma unroll
      for (int g = 0; g < 4; ++g) {
        wl[0][cblk][g] = cvt_pk_bf16(EXP2(s0[4 * g + 0]), EXP2(s0[4 * g + 1]));
        wh[0][cblk][g] = cvt_pk_bf16(EXP2(s0[4 * g + 2]), EXP2(s0[4 * g + 3]));
        wl[1][cblk][g] = cvt_pk_bf16(EXP2(s1[4 * g + 0]), EXP2(s1[4 * g + 1]));
        wh[1][cblk][g] = cvt_pk_bf16(EXP2(s1[4 * g + 2]), EXP2(s1[4 * g + 3]));
      }
    }
    // ---- PV: 4 K=16 chunks; B-frags via permlane32_swap; vf shared by sets ----
#pragma unroll
    for (int ct = 0; ct < 4; ++ct) {
      int cb = ct >> 1, sh = ct & 1;
      u32 p00 = wl[0][cb][2 * sh], p01 = wl[0][cb][2 * sh + 1];
      u32 p02 = wh[0][cb][2 * sh], p03 = wh[0][cb][2 * sh + 1];
      permswap32(p00, p01);
      permswap32(p02, p03);
      union { u32 wd[4]; bf16x8 v; } pf0;
      pf0.wd[0] = p00; pf0.wd[1] = p02; pf0.wd[2] = p01; pf0.wd[3] = p03;
      u32 p10 = wl[1][cb][2 * sh], p11 = wl[1][cb][2 * sh + 1];
      u32 p12 = wh[1][cb][2 * sh], p13 = wh[1][cb][2 * sh + 1];
      permswap32(p10, p11);
      permswap32(p12, p13);
      union { u32 wd[4]; bf16x8 v; } pf1;
      pf1.wd[0] = p10; pf1.wd[1] = p12; pf1.wd[2] = p11; pf1.wd[3] = p13;
#pragma unroll
      for (int dblk = 0; dblk < 2; ++dblk) {
        int vrow = dblk * 32 + l31;
        int vw = (vrow & 7) << 4;
        bf16x8 vf = *(const bf16x8*)(vb + vrow * 128 + ((ct * 32 + hi * 16) ^ vw));
        oacc[0][dblk] = MFMA32(vf, pf0.v, oacc[0][dblk]);
        oacc[1][dblk] = MFMA32(vf, pf1.v, oacc[1][dblk]);
      }
    }
    __syncthreads();
  }
  // ---- store: q = qg + s*32, d = dblk*32 + 8g + 4hi + m ----
#pragma unroll
  for (int s = 0; s < 2; ++s)
#pragma unroll
    for (int dblk = 0; dblk < 2; ++dblk)
#pragma unroll
      for (int g = 0; g < 4; ++g) {
        union { __bf16 h4[4]; uint2 u; } pk;
#pragma unroll
        for (int m = 0; m < 4; ++m) pk.h4[m] = (__bf16)oacc[s][dblk][4 * g + m];
        int d = dblk * 32 + 8 * g + 4 * hi;
        size_t addr = ((size_t)b * N + qg + s * 32) * C + h * 64 + d;
        *reinterpret_cast<uint2*>(&out[addr]) = pk.u;
      }
}

extern "C" void kernel_launch(void* const* d_in, const int* in_sizes, int n_in,
                              void* d_out, int out_size, void* d_ws, size_t ws_size,
                              hipStream_t stream) {
  (void)in_sizes; (void)n_in; (void)out_size; (void)ws_size;
  const float* x1  = (const float*)d_in[0];
  const float* x2  = (const float*)d_in[1];
  const float* Wq  = (const float*)d_in[2];
  const float* bq  = (const float*)d_in[3];
  const float* Wk  = (const float*)d_in[4];
  const float* bk  = (const float*)d_in[5];
  const float* Wv1 = (const float*)d_in[6];
  const float* bv1 = (const float*)d_in[7];
  const float* Wv2 = (const float*)d_in[8];
  const float* bv2 = (const float*)d_in[9];
  const float* Wo1 = (const float*)d_in[10];
  const float* bo1 = (const float*)d_in[11];
  const float* Wo2 = (const float*)d_in[12];
  const float* bo2 = (const float*)d_in[13];

  char* ws = (char*)d_ws;
  __bf16* ht1  = (__bf16*)(ws + OFF_HT1);
  __bf16* ht2  = (__bf16*)(ws + OFF_HT2);
  __bf16* qb   = (__bf16*)(ws + OFF_Q);
  __bf16* kb   = (__bf16*)(ws + OFF_K);
  __bf16* vt1  = (__bf16*)(ws + OFF_VT1);
  __bf16* vt2  = (__bf16*)(ws + OFF_VT2);
  __bf16* ctx1 = (__bf16*)(ws + OFF_CTX1);
  __bf16* ctx2 = (__bf16*)(ws + OFF_CTX2);
  __bf16* wqt  = (__bf16*)(ws + OFF_WQT);
  __bf16* wkt  = (__bf16*)(ws + OFF_WKT);
  __bf16* wv1t = (__bf16*)(ws + OFF_WV1T);
  __bf16* wv2t = (__bf16*)(ws + OFF_WV2T);
  __bf16* wo1t = (__bf16*)(ws + OFF_WO1T);
  __bf16* wo2t = (__bf16*)(ws + OFF_WO2T);
  float* qrs = (float*)(ws + OFF_QRS);
  float* krs = (float*)(ws + OFF_KRS);
  float* outf = (float*)d_out;

  dim3 blk(256);
  k_tc2<<<dim3(32, 8, 8), blk, 0, stream>>>(x1, x2, ht1, ht2);
  WT6 wt;
  wt.src[0] = Wq;  wt.dst[0] = wqt;
  wt.src[1] = Wk;  wt.dst[1] = wkt;
  wt.src[2] = Wv1; wt.dst[2] = wv1t;
  wt.src[3] = Wv2; wt.dst[3] = wv2t;
  wt.src[4] = Wo1; wt.dst[4] = wo1t;
  wt.src[5] = Wo2; wt.dst[5] = wo2t;
  k_tcw<<<dim3(8, 8, 6), blk, 0, stream>>>(wt);

  // q pre-scaled by 0.125*log2(e); k unscaled
  GArgs gq0{ht1, wqt, bq, nullptr, qb, nullptr, nullptr, SM_C};
  GArgs gq1{ht2, wkt, bk, nullptr, kb, nullptr, nullptr, 1.0f};
  k_gemm<0><<<512, blk, 0, stream>>>(gq0, gq1);

  // qrs[q] = 1/sum_k exp2(S*c) ; krs[k] = 1/sum_q exp2(S*c)
  SArgs st0{qb, kb, qrs};
  SArgs st1{kb, qb, krs};
  k_stats<<<512, blk, 0, stream>>>(st0, st1);

  // V projections with 1/sum folded in per token: v1 scaled by krs, v2 by qrs
  GArgs gv0{ht1, wv1t, bv1, krs, vt1, nullptr, nullptr, 0.f};
  GArgs gv1{ht2, wv2t, bv2, qrs, vt2, nullptr, nullptr, 0.f};
  k_gemm<1><<<512, blk, 0, stream>>>(gv0, gv1);

  // ctx1[q,d] = sum_k exp2(Sc)*v1'[k,d]; ctx2[k,d] = sum_q exp2(Sc)*v2'[q,d]
  CArgs cc0{qb, kb, vt1, ctx1};
  CArgs cc1{kb, qb, vt2, ctx2};
  k_ctx<<<512, blk, 0, stream>>>(cc0, cc1);

  GArgs go0{ctx1, wo1t, bo1, nullptr, nullptr, outf, x1, 0.f};
  GArgs go1{ctx2, wo2t, bo2, nullptr, nullptr, outf + BCN, x2, 0.f};
  k_gemm<2><<<512, blk, 0, stream>>>(go0, go1);
}